// Round 1
// baseline (2946.490 us; speedup 1.0000x reference)
//
#include <hip/hip_runtime.h>

typedef unsigned short u16;
typedef unsigned int u32;
typedef __attribute__((ext_vector_type(8))) short bf16x8;
typedef __attribute__((ext_vector_type(4))) float f32x4;

#define SEQ 1024
#define DM 768
#define NH 12
#define HD2 64
#define NLAYER 4
#define NVOCAB 50257
#define BT 2048  // B*T

__device__ __forceinline__ u16 f2bf(float f) {
  union { float f; u32 u; } v; v.f = f;
  u32 r = v.u + 0x7FFFu + ((v.u >> 16) & 1u);
  return (u16)(r >> 16);
}
__device__ __forceinline__ float bf2f(u16 u) {
  union { u32 u; float f; } v; v.u = ((u32)u) << 16;
  return v.f;
}

// ---------------- embedding ----------------
__global__ void k_embed(const int* __restrict__ idx, const float* __restrict__ wte,
                        float* __restrict__ xf) {
  int r = blockIdx.x;
  int tok = idx[r];
  const float* s = wte + (size_t)tok * DM;
  float* d = xf + (size_t)r * DM;
  for (int c = threadIdx.x; c < DM; c += 256) d[c] = s[c];
}

// ---------------- block reductions (256 thr = 4 waves) ----------------
__device__ __forceinline__ float bsum(float v, float* red) {
#pragma unroll
  for (int o = 32; o > 0; o >>= 1) v += __shfl_down(v, o);
  if ((threadIdx.x & 63) == 0) red[threadIdx.x >> 6] = v;
  __syncthreads();
  if (threadIdx.x == 0) red[4] = red[0] + red[1] + red[2] + red[3];
  __syncthreads();
  return red[4];
}
__device__ __forceinline__ float bmax(float v, float* red) {
#pragma unroll
  for (int o = 32; o > 0; o >>= 1) v = fmaxf(v, __shfl_down(v, o));
  if ((threadIdx.x & 63) == 0) red[threadIdx.x >> 6] = v;
  __syncthreads();
  if (threadIdx.x == 0) red[4] = fmaxf(fmaxf(red[0], red[1]), fmaxf(red[2], red[3]));
  __syncthreads();
  return red[4];
}

// ---------------- dual layernorm (both read same x) ----------------
__global__ void k_ln(const float* __restrict__ x, const float* __restrict__ g1,
                     const float* __restrict__ b1, const float* __restrict__ g2,
                     const float* __restrict__ b2, u16* __restrict__ o1,
                     u16* __restrict__ o2) {
  __shared__ float red[8];
  int r = blockIdx.x;
  int t = threadIdx.x;
  const float* xr = x + (size_t)r * DM;
  float v0 = xr[t], v1 = xr[t + 256], v2 = xr[t + 512];
  float mean = bsum(v0 + v1 + v2, red) * (1.f / DM);
  float d0 = v0 - mean, d1 = v1 - mean, d2 = v2 - mean;
  float var = bsum(d0 * d0 + d1 * d1 + d2 * d2, red) * (1.f / DM);
  float rstd = rsqrtf(var + 1e-5f);
  u16* p1 = o1 + (size_t)r * DM;
  p1[t]       = f2bf(d0 * rstd * g1[t]       + b1[t]);
  p1[t + 256] = f2bf(d1 * rstd * g1[t + 256] + b1[t + 256]);
  p1[t + 512] = f2bf(d2 * rstd * g1[t + 512] + b1[t + 512]);
  if (o2) {
    u16* p2 = o2 + (size_t)r * DM;
    p2[t]       = f2bf(d0 * rstd * g2[t]       + b2[t]);
    p2[t + 256] = f2bf(d1 * rstd * g2[t + 256] + b2[t + 256]);
    p2[t + 512] = f2bf(d2 * rstd * g2[t + 512] + b2[t + 512]);
  }
}

// ---------------- partial RoPE on q,k ----------------
__global__ void k_rope(const u16* __restrict__ qkvb, u16* __restrict__ qr,
                       u16* __restrict__ kr) {
  int gid = blockIdx.x * 256 + threadIdx.x;  // over B*T*NH*32
  int j = gid & 31;
  int h = (gid >> 5) % NH;
  int t = (gid / (32 * NH)) & (SEQ - 1);
  int b = gid / (32 * NH * SEQ);
  float c = 1.f, s = 0.f;
  if (j < 16) {
    float inv = powf(10000.f, -(float)j * (1.f / 32.f));
    float ang = (float)t * inv;
    c = cosf(ang);
    s = sinf(ang);
  }
  size_t base = (size_t)(b * SEQ + t) * (3 * DM);
  size_t ob = ((size_t)(b * NH + h) * SEQ + t) * HD2 + j;
  {
    float a0 = bf2f(qkvb[base + h * HD2 + j]);
    float a1 = bf2f(qkvb[base + h * HD2 + j + 32]);
    qr[ob] = f2bf(a0 * c - a1 * s);
    qr[ob + 32] = f2bf(a1 * c + a0 * s);
  }
  {
    float a0 = bf2f(qkvb[base + DM + h * HD2 + j]);
    float a1 = bf2f(qkvb[base + DM + h * HD2 + j + 32]);
    kr[ob] = f2bf(a0 * c - a1 * s);
    kr[ob + 32] = f2bf(a1 * c + a0 * s);
  }
}

// ---------------- v transpose: [B,T,H,HD] slice -> [B,H,HD,T] ----------------
__global__ void k_vtrans(const u16* __restrict__ qkvb, u16* __restrict__ vT) {
  __shared__ u16 tile[64][65];
  int t0 = blockIdx.x * 64;
  int bh = blockIdx.y;
  int b = bh / NH, h = bh % NH;
  int rr = threadIdx.x >> 2, seg = threadIdx.x & 3;
  const u16* src = qkvb + (size_t)(b * SEQ + t0 + rr) * (3 * DM) + 2 * DM + h * HD2;
#pragma unroll
  for (int i = 0; i < 16; ++i) tile[rr][seg * 16 + i] = src[seg * 16 + i];
  __syncthreads();
  u16* dst = vT + ((size_t)bh * HD2 + rr) * SEQ + t0;
#pragma unroll
  for (int i = 0; i < 16; ++i) dst[seg * 16 + i] = tile[seg * 16 + i][rr];
}

// ---------------- QK^T scores (causal lower-tri tiles) ----------------
__global__ void k_qk(const u16* __restrict__ qr, const u16* __restrict__ kr,
                     u16* __restrict__ sc) {
  int tj = blockIdx.x, ti = blockIdx.y, bh = blockIdx.z;
  if (tj > ti) return;
  __shared__ u16 Qs[64 * 72];
  __shared__ u16 Ks[64 * 72];
  int tid = threadIdx.x;
  int rr = tid >> 2, cc = tid & 3;
  {
    const u16* gq = qr + ((size_t)bh * SEQ + ti * 64 + rr) * HD2;
    const u16* gk = kr + ((size_t)bh * SEQ + tj * 64 + rr) * HD2;
    *(uint4*)&Qs[rr * 72 + cc * 8]      = *(const uint4*)(gq + cc * 8);
    *(uint4*)&Qs[rr * 72 + cc * 8 + 32] = *(const uint4*)(gq + cc * 8 + 32);
    *(uint4*)&Ks[rr * 72 + cc * 8]      = *(const uint4*)(gk + cc * 8);
    *(uint4*)&Ks[rr * 72 + cc * 8 + 32] = *(const uint4*)(gk + cc * 8 + 32);
  }
  __syncthreads();
  int wid = tid >> 6, lane = tid & 63;
  int rl = lane & 15, g = lane >> 4;
  f32x4 acc[4] = {};
#pragma unroll
  for (int ks = 0; ks < 2; ++ks) {
    bf16x8 a = *(const bf16x8*)&Qs[(wid * 16 + rl) * 72 + ks * 32 + g * 8];
#pragma unroll
    for (int nt = 0; nt < 4; ++nt) {
      bf16x8 bb = *(const bf16x8*)&Ks[(nt * 16 + rl) * 72 + ks * 32 + g * 8];
      acc[nt] = __builtin_amdgcn_mfma_f32_16x16x32_bf16(a, bb, acc[nt], 0, 0, 0);
    }
  }
#pragma unroll
  for (int nt = 0; nt < 4; ++nt) {
    int col = tj * 64 + nt * 16 + rl;
#pragma unroll
    for (int r2 = 0; r2 < 4; ++r2) {
      int row = ti * 64 + wid * 16 + g * 4 + r2;
      sc[((size_t)bh * SEQ + row) * SEQ + col] = f2bf(acc[nt][r2] * 0.125f);
    }
  }
}

// ---------------- causal row softmax (in place, zero-fill to tile bound) ------
__global__ void k_softmax(u16* __restrict__ sc) {
  __shared__ float sv[SEQ];
  __shared__ float red[8];
  int i = blockIdx.x, bh = blockIdx.y;
  int nv = i + 1;
  u16* row = sc + ((size_t)bh * SEQ + i) * SEQ;
  float lm = -3.4e38f;
  for (int j = threadIdx.x; j < nv; j += 256) {
    float v = bf2f(row[j]);
    sv[j] = v;
    lm = fmaxf(lm, v);
  }
  float m = bmax(lm, red);
  float ls = 0.f;
  for (int j = threadIdx.x; j < nv; j += 256) {
    float e = expf(sv[j] - m);
    sv[j] = e;
    ls += e;
  }
  float inv = 1.f / bsum(ls, red);
  for (int j = threadIdx.x; j < nv; j += 256) row[j] = f2bf(sv[j] * inv);
  int nfill = (i / 64 + 1) * 64;
  for (int j = nv + threadIdx.x; j < nfill; j += 256) row[j] = 0;
}

// ---------------- PV: y = probs @ v ----------------
__global__ void k_pv(const u16* __restrict__ pr, const u16* __restrict__ vT,
                     u16* __restrict__ yb) {
  int ti = blockIdx.x, bh = blockIdx.y;
  __shared__ u16 Ps[64 * 72];
  __shared__ u16 Vs[64 * 72];
  int tid = threadIdx.x;
  int rr = tid >> 2, cc = tid & 3;
  int wid = tid >> 6, lane = tid & 63;
  int rl = lane & 15, g = lane >> 4;
  f32x4 acc[4] = {};
  const u16* gp = pr + ((size_t)bh * SEQ + ti * 64 + rr) * SEQ;
  const u16* gv = vT + ((size_t)bh * HD2 + rr) * SEQ;
  for (int kt = 0; kt <= ti; ++kt) {
    __syncthreads();
    *(uint4*)&Ps[rr * 72 + cc * 8]      = *(const uint4*)(gp + kt * 64 + cc * 8);
    *(uint4*)&Ps[rr * 72 + cc * 8 + 32] = *(const uint4*)(gp + kt * 64 + cc * 8 + 32);
    *(uint4*)&Vs[rr * 72 + cc * 8]      = *(const uint4*)(gv + kt * 64 + cc * 8);
    *(uint4*)&Vs[rr * 72 + cc * 8 + 32] = *(const uint4*)(gv + kt * 64 + cc * 8 + 32);
    __syncthreads();
#pragma unroll
    for (int ks = 0; ks < 2; ++ks) {
      bf16x8 a = *(const bf16x8*)&Ps[(wid * 16 + rl) * 72 + ks * 32 + g * 8];
#pragma unroll
      for (int nt = 0; nt < 4; ++nt) {
        bf16x8 bb = *(const bf16x8*)&Vs[(nt * 16 + rl) * 72 + ks * 32 + g * 8];
        acc[nt] = __builtin_amdgcn_mfma_f32_16x16x32_bf16(a, bb, acc[nt], 0, 0, 0);
      }
    }
  }
  int b = bh / NH, h = bh % NH;
#pragma unroll
  for (int nt = 0; nt < 4; ++nt) {
    int d = nt * 16 + rl;
#pragma unroll
    for (int r2 = 0; r2 < 4; ++r2) {
      int trow = ti * 64 + wid * 16 + g * 4 + r2;
      yb[((size_t)(b * SEQ + trow)) * DM + h * HD2 + d] = f2bf(acc[nt][r2]);
    }
  }
}

// ---------------- generic GEMM: C[M,N] = A_bf16[M,K] * B_f32[K,N] + bias -----
// modes: 0 = bf16 out; 1 = bf16 gelu out; 2 = f32 residual add (outf += v);
//        3 = f32 plain out
__global__ void k_gemm(const u16* __restrict__ A, const float* __restrict__ B,
                       const float* __restrict__ bias, u16* __restrict__ outb,
                       float* __restrict__ outf, int M, int N, int K, int mode) {
  __shared__ u16 As[128 * 40];       // [row][k], stride 40 u16 (80 B)
  __shared__ u16 Bs[4 * 128 * 12];   // [g][n][8k + 4 pad], row stride 24 B
  int tid = threadIdx.x;
  int wid = tid >> 6, lane = tid & 63;
  int rl = lane & 15, g = lane >> 4;
  int m0 = blockIdx.x * 128, n0 = blockIdx.y * 128;
  int wm = (wid >> 1) * 64, wn = (wid & 1) * 64;
  int ar = tid >> 2, ac = tid & 3;      // A staging: rows ar, ar+64; 16B chunk ac
  int bn = tid & 127, bq = tid >> 7;    // B staging: n row, k-quad phase
  f32x4 acc[4][4] = {};
  int nK = K / 32;
  for (int kt = 0; kt < nK; ++kt) {
    __syncthreads();
    {
      const u16* ga = A + (size_t)(m0 + ar) * K + kt * 32 + ac * 8;
      *(uint4*)&As[ar * 40 + ac * 8] = *(const uint4*)ga;
      *(uint4*)&As[(ar + 64) * 40 + ac * 8] = *(const uint4*)(ga + (size_t)64 * K);
    }
    int col = n0 + bn;
#pragma unroll
    for (int r = 0; r < 4; ++r) {
      int kq = bq + 2 * r;  // 0..7 across bq
      int kk = kt * 32 + kq * 4;
      float f0 = 0.f, f1 = 0.f, f2v = 0.f, f3 = 0.f;
      if (col < N) {
        const float* gb = B + (size_t)kk * N + col;
        f0 = gb[0];
        f1 = gb[(size_t)N];
        f2v = gb[(size_t)2 * N];
        f3 = gb[(size_t)3 * N];
      }
      uint2 w;
      w.x = (u32)f2bf(f0) | ((u32)f2bf(f1) << 16);
      w.y = (u32)f2bf(f2v) | ((u32)f2bf(f3) << 16);
      *(uint2*)&Bs[(kq >> 1) * 1536 + bn * 12 + (kq & 1) * 4] = w;
    }
    __syncthreads();
    bf16x8 af[4], bfr[4];
#pragma unroll
    for (int mt = 0; mt < 4; ++mt)
      af[mt] = *(const bf16x8*)&As[(wm + mt * 16 + rl) * 40 + g * 8];
#pragma unroll
    for (int nt = 0; nt < 4; ++nt) {
      const u16* p = &Bs[g * 1536 + (wn + nt * 16 + rl) * 12];
      union { bf16x8 v; uint2 u2[2]; } tmp;
      tmp.u2[0] = *(const uint2*)p;
      tmp.u2[1] = *(const uint2*)(p + 4);
      bfr[nt] = tmp.v;
    }
#pragma unroll
    for (int mt = 0; mt < 4; ++mt)
#pragma unroll
      for (int nt = 0; nt < 4; ++nt)
        acc[mt][nt] = __builtin_amdgcn_mfma_f32_16x16x32_bf16(af[mt], bfr[nt],
                                                              acc[mt][nt], 0, 0, 0);
  }
#pragma unroll
  for (int mt = 0; mt < 4; ++mt) {
#pragma unroll
    for (int nt = 0; nt < 4; ++nt) {
      int col = n0 + wn + nt * 16 + rl;
      if (col >= N) continue;
      float bv = bias ? bias[col] : 0.f;
#pragma unroll
      for (int r2 = 0; r2 < 4; ++r2) {
        int row = m0 + wm + mt * 16 + g * 4 + r2;
        float v = acc[mt][nt][r2] + bv;
        size_t oi = (size_t)row * N + col;
        if (mode == 0) {
          outb[oi] = f2bf(v);
        } else if (mode == 1) {
          float u = 0.7978845608028654f * (v + 0.044715f * v * v * v);
          outb[oi] = f2bf(0.5f * v * (1.f + tanhf(u)));
        } else if (mode == 2) {
          outf[oi] += v;
        } else {
          outf[oi] = v;
        }
      }
    }
  }
}

extern "C" void kernel_launch(void* const* d_in, const int* in_sizes, int n_in,
                              void* d_out, int out_size, void* d_ws, size_t ws_size,
                              hipStream_t stream) {
  (void)in_sizes; (void)n_in; (void)out_size; (void)ws_size;
  const int*   idx  = (const int*)  d_in[0];
  const float* wte  = (const float*)d_in[1];
  const float* ln1g = (const float*)d_in[2];
  const float* ln1b = (const float*)d_in[3];
  const float* Wqkv = (const float*)d_in[4];
  const float* bqkv = (const float*)d_in[5];
  const float* Wo   = (const float*)d_in[6];
  const float* bo   = (const float*)d_in[7];
  const float* ln2g = (const float*)d_in[8];
  const float* ln2b = (const float*)d_in[9];
  const float* Wfc  = (const float*)d_in[10];
  const float* bfc  = (const float*)d_in[11];
  const float* Wp   = (const float*)d_in[12];
  const float* bp   = (const float*)d_in[13];
  const float* lnfg = (const float*)d_in[14];
  const float* lnfb = (const float*)d_in[15];
  const float* Wlm  = (const float*)d_in[16];
  float* out = (float*)d_out;

  // Scratch packed into d_out (all dead before the logits GEMM rewrites d_out).
  char* sb = (char*)d_out;
  size_t off = 0;
  auto alloc = [&](size_t bytes) {
    char* p = sb + off;
    off += (bytes + 255) & ~(size_t)255;
    return (void*)p;
  };
  float* xf  = (float*)alloc((size_t)BT * DM * 4);
  u16* h1b   = (u16*)alloc((size_t)BT * DM * 2);
  u16* h2b   = (u16*)alloc((size_t)BT * DM * 2);
  u16* qkvb  = (u16*)alloc((size_t)BT * 3 * DM * 2);
  u16* qr    = (u16*)alloc((size_t)BT * DM * 2);
  u16* kr    = (u16*)alloc((size_t)BT * DM * 2);
  u16* vT    = (u16*)alloc((size_t)BT * DM * 2);
  u16* sc    = (u16*)alloc((size_t)2 * NH * SEQ * SEQ * 2);
  u16* yb    = (u16*)alloc((size_t)BT * DM * 2);
  u16* hgel  = (u16*)alloc((size_t)BT * 4 * DM * 2);
  u16* xlnf  = (u16*)d_ws;  // must survive the logits GEMM -> lives in ws

  k_embed<<<BT, 256, 0, stream>>>(idx, wte, xf);
  for (int l = 0; l < NLAYER; ++l) {
    k_ln<<<BT, 256, 0, stream>>>(xf, ln1g + l * DM, ln1b + l * DM,
                                 ln2g + l * DM, ln2b + l * DM, h1b, h2b);
    k_gemm<<<dim3(BT / 128, (3 * DM) / 128), 256, 0, stream>>>(
        h1b, Wqkv + (size_t)l * DM * 3 * DM, bqkv + (size_t)l * 3 * DM,
        qkvb, nullptr, BT, 3 * DM, DM, 0);
    k_rope<<<(2 * SEQ * NH * 32) / 256, 256, 0, stream>>>(qkvb, qr, kr);
    k_vtrans<<<dim3(SEQ / 64, 2 * NH), 256, 0, stream>>>(qkvb, vT);
    k_qk<<<dim3(16, 16, 2 * NH), 256, 0, stream>>>(qr, kr, sc);
    k_softmax<<<dim3(SEQ, 2 * NH), 256, 0, stream>>>(sc);
    k_pv<<<dim3(16, 2 * NH), 256, 0, stream>>>(sc, vT, yb);
    k_gemm<<<dim3(BT / 128, DM / 128), 256, 0, stream>>>(
        yb, Wo + (size_t)l * DM * DM, bo + (size_t)l * DM,
        nullptr, xf, BT, DM, DM, 2);
    k_gemm<<<dim3(BT / 128, (4 * DM) / 128), 256, 0, stream>>>(
        h2b, Wfc + (size_t)l * DM * 4 * DM, bfc + (size_t)l * 4 * DM,
        hgel, nullptr, BT, 4 * DM, DM, 1);
    k_gemm<<<dim3(BT / 128, DM / 128), 256, 0, stream>>>(
        hgel, Wp + (size_t)l * 4 * DM * DM, bp + (size_t)l * DM,
        nullptr, xf, BT, DM, 4 * DM, 2);
  }
  k_ln<<<BT, 256, 0, stream>>>(xf, lnfg, lnfb, nullptr, nullptr, xlnf, nullptr);
  k_gemm<<<dim3(BT / 128, (NVOCAB + 127) / 128), 256, 0, stream>>>(
      xlnf, Wlm, nullptr, nullptr, out, BT, NVOCAB, DM, 3);
}

// Round 2
// 1551.115 us; speedup vs baseline: 1.8996x; 1.8996x over previous
//
#include <hip/hip_runtime.h>

typedef unsigned short u16;
typedef unsigned int u32;
typedef __attribute__((ext_vector_type(8))) short bf16x8;
typedef __attribute__((ext_vector_type(4))) float f32x4;

#define SEQ 1024
#define DM 768
#define NH 12
#define HD2 64
#define NLAYER 4
#define NVOCAB 50257
#define BT 2048  // B*T

__device__ __forceinline__ u16 f2bf(float f) {
  union { float f; u32 u; } v; v.f = f;
  u32 r = v.u + 0x7FFFu + ((v.u >> 16) & 1u);
  return (u16)(r >> 16);
}
__device__ __forceinline__ float bf2f(u16 u) {
  union { u32 u; float f; } v; v.u = ((u32)u) << 16;
  return v.f;
}

__device__ __forceinline__ void glds16(const u16* g, u16* l) {
  __builtin_amdgcn_global_load_lds(
      (const __attribute__((address_space(1))) u32*)(const void*)g,
      (__attribute__((address_space(3))) u32*)(void*)l, 16, 0, 0);
}

// ---------------- embedding ----------------
__global__ void k_embed(const int* __restrict__ idx, const float* __restrict__ wte,
                        float* __restrict__ xf) {
  int r = blockIdx.x;
  int tok = idx[r];
  const float* s = wte + (size_t)tok * DM;
  float* d = xf + (size_t)r * DM;
  for (int c = threadIdx.x; c < DM; c += 256) d[c] = s[c];
}

// ---------------- transpose + f32->bf16: in[R,C] f32 -> out[C,R] bf16 -------
__global__ void k_cvtT(const float* __restrict__ in, u16* __restrict__ out,
                       int R, int C) {
  __shared__ u16 t[32][34];
  int c0 = blockIdx.x * 32, r0 = blockIdx.y * 32;
  int tx = threadIdx.x & 31, ty = threadIdx.x >> 5;  // ty in 0..7
#pragma unroll
  for (int i = 0; i < 4; ++i) {
    int r = r0 + ty + i * 8, c = c0 + tx;
    float v = (c < C) ? in[(size_t)r * C + c] : 0.f;  // R always multiple of 32
    t[ty + i * 8][tx] = f2bf(v);
  }
  __syncthreads();
#pragma unroll
  for (int i = 0; i < 4; ++i) {
    int c = c0 + ty + i * 8, r = r0 + tx;
    if (c < C) out[(size_t)c * R + r] = t[tx][ty + i * 8];
  }
}

// ---------------- block reductions (256 thr = 4 waves) ----------------
__device__ __forceinline__ float bsum(float v, float* red) {
#pragma unroll
  for (int o = 32; o > 0; o >>= 1) v += __shfl_down(v, o);
  if ((threadIdx.x & 63) == 0) red[threadIdx.x >> 6] = v;
  __syncthreads();
  if (threadIdx.x == 0) red[4] = red[0] + red[1] + red[2] + red[3];
  __syncthreads();
  return red[4];
}
__device__ __forceinline__ float bmax(float v, float* red) {
#pragma unroll
  for (int o = 32; o > 0; o >>= 1) v = fmaxf(v, __shfl_down(v, o));
  if ((threadIdx.x & 63) == 0) red[threadIdx.x >> 6] = v;
  __syncthreads();
  if (threadIdx.x == 0) red[4] = fmaxf(fmaxf(red[0], red[1]), fmaxf(red[2], red[3]));
  __syncthreads();
  return red[4];
}

// ---------------- dual layernorm (both read same x) ----------------
__global__ void k_ln(const float* __restrict__ x, const float* __restrict__ g1,
                     const float* __restrict__ b1, const float* __restrict__ g2,
                     const float* __restrict__ b2, u16* __restrict__ o1,
                     u16* __restrict__ o2) {
  __shared__ float red[8];
  int r = blockIdx.x;
  int t = threadIdx.x;
  const float* xr = x + (size_t)r * DM;
  float v0 = xr[t], v1 = xr[t + 256], v2 = xr[t + 512];
  float mean = bsum(v0 + v1 + v2, red) * (1.f / DM);
  float d0 = v0 - mean, d1 = v1 - mean, d2 = v2 - mean;
  float var = bsum(d0 * d0 + d1 * d1 + d2 * d2, red) * (1.f / DM);
  float rstd = rsqrtf(var + 1e-5f);
  u16* p1 = o1 + (size_t)r * DM;
  p1[t]       = f2bf(d0 * rstd * g1[t]       + b1[t]);
  p1[t + 256] = f2bf(d1 * rstd * g1[t + 256] + b1[t + 256]);
  p1[t + 512] = f2bf(d2 * rstd * g1[t + 512] + b1[t + 512]);
  if (o2) {
    u16* p2 = o2 + (size_t)r * DM;
    p2[t]       = f2bf(d0 * rstd * g2[t]       + b2[t]);
    p2[t + 256] = f2bf(d1 * rstd * g2[t + 256] + b2[t + 256]);
    p2[t + 512] = f2bf(d2 * rstd * g2[t + 512] + b2[t + 512]);
  }
}

// ---------------- partial RoPE on q,k ----------------
__global__ void k_rope(const u16* __restrict__ qkvb, u16* __restrict__ qr,
                       u16* __restrict__ kr) {
  int gid = blockIdx.x * 256 + threadIdx.x;  // over B*T*NH*32
  int j = gid & 31;
  int h = (gid >> 5) % NH;
  int t = (gid / (32 * NH)) & (SEQ - 1);
  int b = gid / (32 * NH * SEQ);
  float c = 1.f, s = 0.f;
  if (j < 16) {
    float inv = powf(10000.f, -(float)j * (1.f / 32.f));
    float ang = (float)t * inv;
    c = cosf(ang);
    s = sinf(ang);
  }
  size_t base = (size_t)(b * SEQ + t) * (3 * DM);
  size_t ob = ((size_t)(b * NH + h) * SEQ + t) * HD2 + j;
  {
    float a0 = bf2f(qkvb[base + h * HD2 + j]);
    float a1 = bf2f(qkvb[base + h * HD2 + j + 32]);
    qr[ob] = f2bf(a0 * c - a1 * s);
    qr[ob + 32] = f2bf(a1 * c + a0 * s);
  }
  {
    float a0 = bf2f(qkvb[base + DM + h * HD2 + j]);
    float a1 = bf2f(qkvb[base + DM + h * HD2 + j + 32]);
    kr[ob] = f2bf(a0 * c - a1 * s);
    kr[ob + 32] = f2bf(a1 * c + a0 * s);
  }
}

// ---------------- v transpose: [B,T,H,HD] slice -> [B,H,HD,T] ----------------
__global__ void k_vtrans(const u16* __restrict__ qkvb, u16* __restrict__ vT) {
  __shared__ u16 tile[64][65];
  int t0 = blockIdx.x * 64;
  int bh = blockIdx.y;
  int b = bh / NH, h = bh % NH;
  int rr = threadIdx.x >> 2, seg = threadIdx.x & 3;
  const u16* src = qkvb + (size_t)(b * SEQ + t0 + rr) * (3 * DM) + 2 * DM + h * HD2;
#pragma unroll
  for (int i = 0; i < 16; ++i) tile[rr][seg * 16 + i] = src[seg * 16 + i];
  __syncthreads();
  u16* dst = vT + ((size_t)bh * HD2 + rr) * SEQ + t0;
#pragma unroll
  for (int i = 0; i < 16; ++i) dst[seg * 16 + i] = tile[seg * 16 + i][rr];
}

// ---------------- QK^T scores (causal lower-tri tiles) ----------------
__global__ void k_qk(const u16* __restrict__ qr, const u16* __restrict__ kr,
                     u16* __restrict__ sc) {
  int tj = blockIdx.x, ti = blockIdx.y, bh = blockIdx.z;
  if (tj > ti) return;
  __shared__ u16 Qs[64 * 72];
  __shared__ u16 Ks[64 * 72];
  int tid = threadIdx.x;
  int rr = tid >> 2, cc = tid & 3;
  {
    const u16* gq = qr + ((size_t)bh * SEQ + ti * 64 + rr) * HD2;
    const u16* gk = kr + ((size_t)bh * SEQ + tj * 64 + rr) * HD2;
    *(uint4*)&Qs[rr * 72 + cc * 8]      = *(const uint4*)(gq + cc * 8);
    *(uint4*)&Qs[rr * 72 + cc * 8 + 32] = *(const uint4*)(gq + cc * 8 + 32);
    *(uint4*)&Ks[rr * 72 + cc * 8]      = *(const uint4*)(gk + cc * 8);
    *(uint4*)&Ks[rr * 72 + cc * 8 + 32] = *(const uint4*)(gk + cc * 8 + 32);
  }
  __syncthreads();
  int wid = tid >> 6, lane = tid & 63;
  int rl = lane & 15, g = lane >> 4;
  f32x4 acc[4] = {};
#pragma unroll
  for (int ks = 0; ks < 2; ++ks) {
    bf16x8 a = *(const bf16x8*)&Qs[(wid * 16 + rl) * 72 + ks * 32 + g * 8];
#pragma unroll
    for (int nt = 0; nt < 4; ++nt) {
      bf16x8 bb = *(const bf16x8*)&Ks[(nt * 16 + rl) * 72 + ks * 32 + g * 8];
      acc[nt] = __builtin_amdgcn_mfma_f32_16x16x32_bf16(a, bb, acc[nt], 0, 0, 0);
    }
  }
#pragma unroll
  for (int nt = 0; nt < 4; ++nt) {
    int col = tj * 64 + nt * 16 + rl;
#pragma unroll
    for (int r2 = 0; r2 < 4; ++r2) {
      int row = ti * 64 + wid * 16 + g * 4 + r2;
      sc[((size_t)bh * SEQ + row) * SEQ + col] = f2bf(acc[nt][r2] * 0.125f);
    }
  }
}

// ---------------- causal row softmax (in place, zero-fill to tile bound) ------
__global__ void k_softmax(u16* __restrict__ sc) {
  __shared__ float sv[SEQ];
  __shared__ float red[8];
  int i = blockIdx.x, bh = blockIdx.y;
  int nv = i + 1;
  u16* row = sc + ((size_t)bh * SEQ + i) * SEQ;
  float lm = -3.4e38f;
  for (int j = threadIdx.x; j < nv; j += 256) {
    float v = bf2f(row[j]);
    sv[j] = v;
    lm = fmaxf(lm, v);
  }
  float m = bmax(lm, red);
  float ls = 0.f;
  for (int j = threadIdx.x; j < nv; j += 256) {
    float e = expf(sv[j] - m);
    sv[j] = e;
    ls += e;
  }
  float inv = 1.f / bsum(ls, red);
  for (int j = threadIdx.x; j < nv; j += 256) row[j] = f2bf(sv[j] * inv);
  int nfill = (i / 64 + 1) * 64;
  for (int j = nv + threadIdx.x; j < nfill; j += 256) row[j] = 0;
}

// ---------------- PV: y = probs @ v ----------------
__global__ void k_pv(const u16* __restrict__ pr, const u16* __restrict__ vT,
                     u16* __restrict__ yb) {
  int ti = blockIdx.x, bh = blockIdx.y;
  __shared__ u16 Ps[64 * 72];
  __shared__ u16 Vs[64 * 72];
  int tid = threadIdx.x;
  int rr = tid >> 2, cc = tid & 3;
  int wid = tid >> 6, lane = tid & 63;
  int rl = lane & 15, g = lane >> 4;
  f32x4 acc[4] = {};
  const u16* gp = pr + ((size_t)bh * SEQ + ti * 64 + rr) * SEQ;
  const u16* gv = vT + ((size_t)bh * HD2 + rr) * SEQ;
  for (int kt = 0; kt <= ti; ++kt) {
    __syncthreads();
    *(uint4*)&Ps[rr * 72 + cc * 8]      = *(const uint4*)(gp + kt * 64 + cc * 8);
    *(uint4*)&Ps[rr * 72 + cc * 8 + 32] = *(const uint4*)(gp + kt * 64 + cc * 8 + 32);
    *(uint4*)&Vs[rr * 72 + cc * 8]      = *(const uint4*)(gv + kt * 64 + cc * 8);
    *(uint4*)&Vs[rr * 72 + cc * 8 + 32] = *(const uint4*)(gv + kt * 64 + cc * 8 + 32);
    __syncthreads();
#pragma unroll
    for (int ks = 0; ks < 2; ++ks) {
      bf16x8 a = *(const bf16x8*)&Ps[(wid * 16 + rl) * 72 + ks * 32 + g * 8];
#pragma unroll
      for (int nt = 0; nt < 4; ++nt) {
        bf16x8 bb = *(const bf16x8*)&Vs[(nt * 16 + rl) * 72 + ks * 32 + g * 8];
        acc[nt] = __builtin_amdgcn_mfma_f32_16x16x32_bf16(a, bb, acc[nt], 0, 0, 0);
      }
    }
  }
  int b = bh / NH, h = bh % NH;
#pragma unroll
  for (int nt = 0; nt < 4; ++nt) {
    int d = nt * 16 + rl;
#pragma unroll
    for (int r2 = 0; r2 < 4; ++r2) {
      int trow = ti * 64 + wid * 16 + g * 4 + r2;
      yb[((size_t)(b * SEQ + trow)) * DM + h * HD2 + d] = f2bf(acc[nt][r2]);
    }
  }
}

// ---------------- m97-style GEMM: C[M,N] = A[M,K]bf16 * BT[N,K]bf16 ----------
// modes: 0 bf16 out; 1 bf16 gelu out; 2 f32 residual add; 3 f32 out
__global__ void k_gemm_bt(const u16* __restrict__ A, const u16* __restrict__ Bt,
                          const float* __restrict__ bias, u16* __restrict__ outb,
                          float* __restrict__ outf, int M, int N, int K, int MT,
                          int mode) {
  __shared__ u16 As[128 * 32];
  __shared__ u16 Bs[128 * 32];
  int nwg = gridDim.x;
  int id = blockIdx.x;
  if ((nwg & 7) == 0) id = (id & 7) * (nwg >> 3) + (id >> 3);  // XCD swizzle
  int mt = id % MT, nt = id / MT;
  int m0 = mt * 128, n0 = nt * 128;
  int tid = threadIdx.x;
  int w = tid >> 6, l = tid & 63;
  int sr = w * 16 + (l >> 2);   // staging row 0..63
  int sc8 = (l & 3) * 8;        // k-chunk within 32
  int nr1 = n0 + sr;      if (nr1 > N - 1) nr1 = N - 1;
  int nr2 = n0 + sr + 64; if (nr2 > N - 1) nr2 = N - 1;
  const u16* gA1 = A + (size_t)(m0 + sr) * K + sc8;
  const u16* gA2 = gA1 + (size_t)64 * K;
  const u16* gB1 = Bt + (size_t)nr1 * K + sc8;
  const u16* gB2 = Bt + (size_t)nr2 * K + sc8;
  u16* lA1 = &As[w * 16 * 32];
  u16* lA2 = &As[(64 + w * 16) * 32];
  u16* lB1 = &Bs[w * 16 * 32];
  u16* lB2 = &Bs[(64 + w * 16) * 32];
  int wm = (w >> 1) * 64, wn = (w & 1) * 64;
  int rl = l & 15, g = l >> 4;
  f32x4 acc[4][4] = {};
  int nK = K >> 5;
  for (int kt = 0; kt < nK; ++kt) {
    __syncthreads();
    glds16(gA1 + kt * 32, lA1);
    glds16(gA2 + kt * 32, lA2);
    glds16(gB1 + kt * 32, lB1);
    glds16(gB2 + kt * 32, lB2);
    __syncthreads();
    bf16x8 af[4], bfr[4];
#pragma unroll
    for (int i = 0; i < 4; ++i)
      af[i] = *(const bf16x8*)&As[(wm + i * 16 + rl) * 32 + g * 8];
#pragma unroll
    for (int i = 0; i < 4; ++i)
      bfr[i] = *(const bf16x8*)&Bs[(wn + i * 16 + rl) * 32 + g * 8];
#pragma unroll
    for (int i = 0; i < 4; ++i)
#pragma unroll
      for (int j = 0; j < 4; ++j)
        acc[i][j] = __builtin_amdgcn_mfma_f32_16x16x32_bf16(af[i], bfr[j],
                                                            acc[i][j], 0, 0, 0);
  }
#pragma unroll
  for (int i = 0; i < 4; ++i) {
#pragma unroll
    for (int j = 0; j < 4; ++j) {
      int col = n0 + wn + j * 16 + rl;
      if (col >= N) continue;
      float bv = bias ? bias[col] : 0.f;
#pragma unroll
      for (int r2 = 0; r2 < 4; ++r2) {
        int row = m0 + wm + i * 16 + g * 4 + r2;
        float v = acc[i][j][r2] + bv;
        size_t oi = (size_t)row * N + col;
        if (mode == 0) {
          outb[oi] = f2bf(v);
        } else if (mode == 1) {
          float u = 0.7978845608028654f * (v + 0.044715f * v * v * v);
          outb[oi] = f2bf(0.5f * v * (1.f + tanhf(u)));
        } else if (mode == 2) {
          outf[oi] += v;
        } else {
          outf[oi] = v;
        }
      }
    }
  }
}

// ---------------- fallback GEMM (f32 B, on-the-fly cvt) — logits only --------
__global__ void k_gemm_f32b(const u16* __restrict__ A, const float* __restrict__ B,
                            float* __restrict__ outf, int M, int N, int K) {
  __shared__ u16 As[128 * 40];
  __shared__ u16 Bs[4 * 128 * 12];
  int tid = threadIdx.x;
  int wid = tid >> 6, lane = tid & 63;
  int rl = lane & 15, g = lane >> 4;
  int m0 = blockIdx.x * 128, n0 = blockIdx.y * 128;
  int wm = (wid >> 1) * 64, wn = (wid & 1) * 64;
  int ar = tid >> 2, ac = tid & 3;
  int bn = tid & 127, bq = tid >> 7;
  f32x4 acc[4][4] = {};
  int nK = K / 32;
  for (int kt = 0; kt < nK; ++kt) {
    __syncthreads();
    {
      const u16* ga = A + (size_t)(m0 + ar) * K + kt * 32 + ac * 8;
      *(uint4*)&As[ar * 40 + ac * 8] = *(const uint4*)ga;
      *(uint4*)&As[(ar + 64) * 40 + ac * 8] = *(const uint4*)(ga + (size_t)64 * K);
    }
    int col = n0 + bn;
#pragma unroll
    for (int r = 0; r < 4; ++r) {
      int kq = bq + 2 * r;
      int kk = kt * 32 + kq * 4;
      float f0 = 0.f, f1 = 0.f, f2v = 0.f, f3 = 0.f;
      if (col < N) {
        const float* gb = B + (size_t)kk * N + col;
        f0 = gb[0]; f1 = gb[(size_t)N]; f2v = gb[(size_t)2 * N]; f3 = gb[(size_t)3 * N];
      }
      uint2 w;
      w.x = (u32)f2bf(f0) | ((u32)f2bf(f1) << 16);
      w.y = (u32)f2bf(f2v) | ((u32)f2bf(f3) << 16);
      *(uint2*)&Bs[(kq >> 1) * 1536 + bn * 12 + (kq & 1) * 4] = w;
    }
    __syncthreads();
    bf16x8 af[4], bfr[4];
#pragma unroll
    for (int mt = 0; mt < 4; ++mt)
      af[mt] = *(const bf16x8*)&As[(wm + mt * 16 + rl) * 40 + g * 8];
#pragma unroll
    for (int nt = 0; nt < 4; ++nt) {
      const u16* p = &Bs[g * 1536 + (wn + nt * 16 + rl) * 12];
      union { bf16x8 v; uint2 u2[2]; } tmp;
      tmp.u2[0] = *(const uint2*)p;
      tmp.u2[1] = *(const uint2*)(p + 4);
      bfr[nt] = tmp.v;
    }
#pragma unroll
    for (int mt = 0; mt < 4; ++mt)
#pragma unroll
      for (int nt = 0; nt < 4; ++nt)
        acc[mt][nt] = __builtin_amdgcn_mfma_f32_16x16x32_bf16(af[mt], bfr[nt],
                                                              acc[mt][nt], 0, 0, 0);
  }
#pragma unroll
  for (int mt = 0; mt < 4; ++mt)
#pragma unroll
    for (int nt = 0; nt < 4; ++nt) {
      int col = n0 + wn + nt * 16 + rl;
      if (col >= N) continue;
#pragma unroll
      for (int r2 = 0; r2 < 4; ++r2) {
        int row = m0 + wm + mt * 16 + g * 4 + r2;
        outf[(size_t)row * N + col] = acc[mt][nt][r2];
      }
    }
}

extern "C" void kernel_launch(void* const* d_in, const int* in_sizes, int n_in,
                              void* d_out, int out_size, void* d_ws, size_t ws_size,
                              hipStream_t stream) {
  (void)in_sizes; (void)n_in; (void)out_size;
  const int*   idx  = (const int*)  d_in[0];
  const float* wte  = (const float*)d_in[1];
  const float* ln1g = (const float*)d_in[2];
  const float* ln1b = (const float*)d_in[3];
  const float* Wqkv = (const float*)d_in[4];
  const float* bqkv = (const float*)d_in[5];
  const float* Wo   = (const float*)d_in[6];
  const float* bo   = (const float*)d_in[7];
  const float* ln2g = (const float*)d_in[8];
  const float* ln2b = (const float*)d_in[9];
  const float* Wfc  = (const float*)d_in[10];
  const float* bfc  = (const float*)d_in[11];
  const float* Wp   = (const float*)d_in[12];
  const float* bp   = (const float*)d_in[13];
  const float* lnfg = (const float*)d_in[14];
  const float* lnfb = (const float*)d_in[15];
  const float* Wlm  = (const float*)d_in[16];
  float* out = (float*)d_out;

  // Scratch packed into d_out (all dead before the logits GEMM rewrites d_out).
  char* sb = (char*)d_out;
  size_t off = 0;
  auto alloc = [&](size_t bytes) {
    char* p = sb + off;
    off += (bytes + 255) & ~(size_t)255;
    return (void*)p;
  };
  float* xf  = (float*)alloc((size_t)BT * DM * 4);
  u16* h1b   = (u16*)alloc((size_t)BT * DM * 2);
  u16* h2b   = (u16*)alloc((size_t)BT * DM * 2);
  u16* qkvb  = (u16*)alloc((size_t)BT * 3 * DM * 2);
  u16* qr    = (u16*)alloc((size_t)BT * DM * 2);
  u16* kr    = (u16*)alloc((size_t)BT * DM * 2);
  u16* vT    = (u16*)alloc((size_t)BT * DM * 2);
  u16* sc    = (u16*)alloc((size_t)2 * NH * SEQ * SEQ * 2);
  u16* yb    = (u16*)alloc((size_t)BT * DM * 2);
  u16* hgel  = (u16*)alloc((size_t)BT * 4 * DM * 2);
  // transposed bf16 weights (also dead before logits GEMM)
  u16* wqkvT = (u16*)alloc((size_t)NLAYER * 3 * DM * DM * 2);
  u16* woT   = (u16*)alloc((size_t)NLAYER * DM * DM * 2);
  u16* wfcT  = (u16*)alloc((size_t)NLAYER * 4 * DM * DM * 2);
  u16* wpT   = (u16*)alloc((size_t)NLAYER * 4 * DM * DM * 2);

  // Wlm^T (77 MB) must survive the logits GEMM -> d_ws if it fits.
  size_t wlmT_bytes = (size_t)NVOCAB * DM * 2;
  size_t xlnf_bytes = (size_t)BT * DM * 2;
  bool fast_lm = ws_size >= wlmT_bytes + xlnf_bytes + 512;
  u16* wlmT = (u16*)d_ws;
  u16* xlnf = fast_lm ? (u16*)((char*)d_ws + ((wlmT_bytes + 255) & ~(size_t)255))
                      : (u16*)d_ws;

  // ---- weight conversion pass ----
  for (int l = 0; l < NLAYER; ++l) {
    k_cvtT<<<dim3((3 * DM + 31) / 32, DM / 32), 256, 0, stream>>>(
        Wqkv + (size_t)l * DM * 3 * DM, wqkvT + (size_t)l * 3 * DM * DM, DM, 3 * DM);
    k_cvtT<<<dim3(DM / 32, DM / 32), 256, 0, stream>>>(
        Wo + (size_t)l * DM * DM, woT + (size_t)l * DM * DM, DM, DM);
    k_cvtT<<<dim3((4 * DM) / 32, DM / 32), 256, 0, stream>>>(
        Wfc + (size_t)l * DM * 4 * DM, wfcT + (size_t)l * 4 * DM * DM, DM, 4 * DM);
    k_cvtT<<<dim3(DM / 32, (4 * DM) / 32), 256, 0, stream>>>(
        Wp + (size_t)l * 4 * DM * DM, wpT + (size_t)l * 4 * DM * DM, 4 * DM, DM);
  }
  if (fast_lm)
    k_cvtT<<<dim3((NVOCAB + 31) / 32, DM / 32), 256, 0, stream>>>(Wlm, wlmT, DM, NVOCAB);

  k_embed<<<BT, 256, 0, stream>>>(idx, wte, xf);
  for (int l = 0; l < NLAYER; ++l) {
    k_ln<<<BT, 256, 0, stream>>>(xf, ln1g + l * DM, ln1b + l * DM,
                                 ln2g + l * DM, ln2b + l * DM, h1b, h2b);
    k_gemm_bt<<<(BT / 128) * (3 * DM / 128), 256, 0, stream>>>(
        h1b, wqkvT + (size_t)l * 3 * DM * DM, bqkv + (size_t)l * 3 * DM,
        qkvb, nullptr, BT, 3 * DM, DM, BT / 128, 0);
    k_rope<<<(2 * SEQ * NH * 32) / 256, 256, 0, stream>>>(qkvb, qr, kr);
    k_vtrans<<<dim3(SEQ / 64, 2 * NH), 256, 0, stream>>>(qkvb, vT);
    k_qk<<<dim3(16, 16, 2 * NH), 256, 0, stream>>>(qr, kr, sc);
    k_softmax<<<dim3(SEQ, 2 * NH), 256, 0, stream>>>(sc);
    k_pv<<<dim3(16, 2 * NH), 256, 0, stream>>>(sc, vT, yb);
    k_gemm_bt<<<(BT / 128) * (DM / 128), 256, 0, stream>>>(
        yb, woT + (size_t)l * DM * DM, bo + (size_t)l * DM,
        nullptr, xf, BT, DM, DM, BT / 128, 2);
    k_gemm_bt<<<(BT / 128) * (4 * DM / 128), 256, 0, stream>>>(
        h2b, wfcT + (size_t)l * 4 * DM * DM, bfc + (size_t)l * 4 * DM,
        hgel, nullptr, BT, 4 * DM, DM, BT / 128, 1);
    k_gemm_bt<<<(BT / 128) * (DM / 128), 256, 0, stream>>>(
        hgel, wpT + (size_t)l * 4 * DM * DM, bp + (size_t)l * DM,
        nullptr, xf, BT, DM, 4 * DM, BT / 128, 2);
  }
  k_ln<<<BT, 256, 0, stream>>>(xf, lnfg, lnfb, nullptr, nullptr, xlnf, nullptr);
  if (fast_lm) {
    int nt = (NVOCAB + 127) / 128;
    k_gemm_bt<<<(BT / 128) * nt, 256, 0, stream>>>(
        xlnf, wlmT, nullptr, nullptr, out, BT, NVOCAB, DM, BT / 128, 3);
  } else {
    k_gemm_f32b<<<dim3(BT / 128, (NVOCAB + 127) / 128), 256, 0, stream>>>(
        xlnf, Wlm, out, BT, NVOCAB, DM);
  }
}

// Round 3
// 1100.703 us; speedup vs baseline: 2.6769x; 1.4092x over previous
//
#include <hip/hip_runtime.h>

typedef unsigned short u16;
typedef unsigned int u32;
typedef __attribute__((ext_vector_type(8))) short bf16x8;
typedef __attribute__((ext_vector_type(4))) float f32x4;

#define SEQ 1024
#define DM 768
#define NH 12
#define HD2 64
#define NLAYER 4
#define NVOCAB 50257
#define BT 2048  // B*T

__device__ __forceinline__ u16 f2bf(float f) {
  union { float f; u32 u; } v; v.f = f;
  u32 r = v.u + 0x7FFFu + ((v.u >> 16) & 1u);
  return (u16)(r >> 16);
}
__device__ __forceinline__ float bf2f(u16 u) {
  union { u32 u; float f; } v; v.u = ((u32)u) << 16;
  return v.f;
}

__device__ __forceinline__ void glds16(const u16* g, u16* l) {
  __builtin_amdgcn_global_load_lds(
      (const __attribute__((address_space(1))) u32*)(const void*)g,
      (__attribute__((address_space(3))) u32*)(void*)l, 16, 0, 0);
}

// ---------------- embedding ----------------
__global__ void k_embed(const int* __restrict__ idx, const float* __restrict__ wte,
                        float* __restrict__ xf) {
  int r = blockIdx.x;
  int tok = idx[r];
  const float* s = wte + (size_t)tok * DM;
  float* d = xf + (size_t)r * DM;
  for (int c = threadIdx.x; c < DM; c += 256) d[c] = s[c];
}

// ---------------- transpose + f32->bf16: in[R,C] f32 -> out[C,R] bf16 -------
__global__ void k_cvtT(const float* __restrict__ in, u16* __restrict__ out,
                       int R, int C) {
  __shared__ u16 t[32][34];
  int c0 = blockIdx.x * 32, r0 = blockIdx.y * 32;
  int tx = threadIdx.x & 31, ty = threadIdx.x >> 5;  // ty in 0..7
#pragma unroll
  for (int i = 0; i < 4; ++i) {
    int r = r0 + ty + i * 8, c = c0 + tx;
    float v = (c < C) ? in[(size_t)r * C + c] : 0.f;  // R always multiple of 32
    t[ty + i * 8][tx] = f2bf(v);
  }
  __syncthreads();
#pragma unroll
  for (int i = 0; i < 4; ++i) {
    int c = c0 + ty + i * 8, r = r0 + tx;
    if (c < C) out[(size_t)c * R + r] = t[tx][ty + i * 8];
  }
}

// ---------------- block reductions (256 thr = 4 waves) ----------------
__device__ __forceinline__ float bsum(float v, float* red) {
#pragma unroll
  for (int o = 32; o > 0; o >>= 1) v += __shfl_down(v, o);
  if ((threadIdx.x & 63) == 0) red[threadIdx.x >> 6] = v;
  __syncthreads();
  if (threadIdx.x == 0) red[4] = red[0] + red[1] + red[2] + red[3];
  __syncthreads();
  return red[4];
}
__device__ __forceinline__ float bmax(float v, float* red) {
#pragma unroll
  for (int o = 32; o > 0; o >>= 1) v = fmaxf(v, __shfl_down(v, o));
  if ((threadIdx.x & 63) == 0) red[threadIdx.x >> 6] = v;
  __syncthreads();
  if (threadIdx.x == 0) red[4] = fmaxf(fmaxf(red[0], red[1]), fmaxf(red[2], red[3]));
  __syncthreads();
  return red[4];
}

// ---------------- dual layernorm (both read same x) ----------------
__global__ void k_ln(const float* __restrict__ x, const float* __restrict__ g1,
                     const float* __restrict__ b1, const float* __restrict__ g2,
                     const float* __restrict__ b2, u16* __restrict__ o1,
                     u16* __restrict__ o2) {
  __shared__ float red[8];
  int r = blockIdx.x;
  int t = threadIdx.x;
  const float* xr = x + (size_t)r * DM;
  float v0 = xr[t], v1 = xr[t + 256], v2 = xr[t + 512];
  float mean = bsum(v0 + v1 + v2, red) * (1.f / DM);
  float d0 = v0 - mean, d1 = v1 - mean, d2 = v2 - mean;
  float var = bsum(d0 * d0 + d1 * d1 + d2 * d2, red) * (1.f / DM);
  float rstd = rsqrtf(var + 1e-5f);
  u16* p1 = o1 + (size_t)r * DM;
  p1[t]       = f2bf(d0 * rstd * g1[t]       + b1[t]);
  p1[t + 256] = f2bf(d1 * rstd * g1[t + 256] + b1[t + 256]);
  p1[t + 512] = f2bf(d2 * rstd * g1[t + 512] + b1[t + 512]);
  if (o2) {
    u16* p2 = o2 + (size_t)r * DM;
    p2[t]       = f2bf(d0 * rstd * g2[t]       + b2[t]);
    p2[t + 256] = f2bf(d1 * rstd * g2[t + 256] + b2[t + 256]);
    p2[t + 512] = f2bf(d2 * rstd * g2[t + 512] + b2[t + 512]);
  }
}

// ---------------- partial RoPE on q,k ----------------
__global__ void k_rope(const u16* __restrict__ qkvb, u16* __restrict__ qr,
                       u16* __restrict__ kr) {
  int gid = blockIdx.x * 256 + threadIdx.x;  // over B*T*NH*32
  int j = gid & 31;
  int h = (gid >> 5) % NH;
  int t = (gid / (32 * NH)) & (SEQ - 1);
  int b = gid / (32 * NH * SEQ);
  float c = 1.f, s = 0.f;
  if (j < 16) {
    float inv = powf(10000.f, -(float)j * (1.f / 32.f));
    float ang = (float)t * inv;
    c = cosf(ang);
    s = sinf(ang);
  }
  size_t base = (size_t)(b * SEQ + t) * (3 * DM);
  size_t ob = ((size_t)(b * NH + h) * SEQ + t) * HD2 + j;
  {
    float a0 = bf2f(qkvb[base + h * HD2 + j]);
    float a1 = bf2f(qkvb[base + h * HD2 + j + 32]);
    qr[ob] = f2bf(a0 * c - a1 * s);
    qr[ob + 32] = f2bf(a1 * c + a0 * s);
  }
  {
    float a0 = bf2f(qkvb[base + DM + h * HD2 + j]);
    float a1 = bf2f(qkvb[base + DM + h * HD2 + j + 32]);
    kr[ob] = f2bf(a0 * c - a1 * s);
    kr[ob + 32] = f2bf(a1 * c + a0 * s);
  }
}

// ---------------- v transpose: [B,T,H,HD] slice -> [B,H,HD,T] ----------------
__global__ void k_vtrans(const u16* __restrict__ qkvb, u16* __restrict__ vT) {
  __shared__ u16 tile[64][65];
  int t0 = blockIdx.x * 64;
  int bh = blockIdx.y;
  int b = bh / NH, h = bh % NH;
  int rr = threadIdx.x >> 2, seg = threadIdx.x & 3;
  const u16* src = qkvb + (size_t)(b * SEQ + t0 + rr) * (3 * DM) + 2 * DM + h * HD2;
#pragma unroll
  for (int i = 0; i < 16; ++i) tile[rr][seg * 16 + i] = src[seg * 16 + i];
  __syncthreads();
  u16* dst = vT + ((size_t)bh * HD2 + rr) * SEQ + t0;
#pragma unroll
  for (int i = 0; i < 16; ++i) dst[seg * 16 + i] = tile[seg * 16 + i][rr];
}

// ---------------- QK^T scores (causal lower-tri tiles) ----------------
__global__ void k_qk(const u16* __restrict__ qr, const u16* __restrict__ kr,
                     u16* __restrict__ sc) {
  int tj = blockIdx.x, ti = blockIdx.y, bh = blockIdx.z;
  if (tj > ti) return;
  __shared__ u16 Qs[64 * 72];
  __shared__ u16 Ks[64 * 72];
  int tid = threadIdx.x;
  int rr = tid >> 2, cc = tid & 3;
  {
    const u16* gq = qr + ((size_t)bh * SEQ + ti * 64 + rr) * HD2;
    const u16* gk = kr + ((size_t)bh * SEQ + tj * 64 + rr) * HD2;
    *(uint4*)&Qs[rr * 72 + cc * 8]      = *(const uint4*)(gq + cc * 8);
    *(uint4*)&Qs[rr * 72 + cc * 8 + 32] = *(const uint4*)(gq + cc * 8 + 32);
    *(uint4*)&Ks[rr * 72 + cc * 8]      = *(const uint4*)(gk + cc * 8);
    *(uint4*)&Ks[rr * 72 + cc * 8 + 32] = *(const uint4*)(gk + cc * 8 + 32);
  }
  __syncthreads();
  int wid = tid >> 6, lane = tid & 63;
  int rl = lane & 15, g = lane >> 4;
  f32x4 acc[4] = {};
#pragma unroll
  for (int ks = 0; ks < 2; ++ks) {
    bf16x8 a = *(const bf16x8*)&Qs[(wid * 16 + rl) * 72 + ks * 32 + g * 8];
#pragma unroll
    for (int nt = 0; nt < 4; ++nt) {
      bf16x8 bb = *(const bf16x8*)&Ks[(nt * 16 + rl) * 72 + ks * 32 + g * 8];
      acc[nt] = __builtin_amdgcn_mfma_f32_16x16x32_bf16(a, bb, acc[nt], 0, 0, 0);
    }
  }
#pragma unroll
  for (int nt = 0; nt < 4; ++nt) {
    int col = tj * 64 + nt * 16 + rl;
#pragma unroll
    for (int r2 = 0; r2 < 4; ++r2) {
      int row = ti * 64 + wid * 16 + g * 4 + r2;
      sc[((size_t)bh * SEQ + row) * SEQ + col] = f2bf(acc[nt][r2] * 0.125f);
    }
  }
}

// ---------------- causal row softmax (in place, zero-fill to tile bound) ------
__global__ void k_softmax(u16* __restrict__ sc) {
  __shared__ float sv[SEQ];
  __shared__ float red[8];
  int i = blockIdx.x, bh = blockIdx.y;
  int nv = i + 1;
  u16* row = sc + ((size_t)bh * SEQ + i) * SEQ;
  float lm = -3.4e38f;
  for (int j = threadIdx.x; j < nv; j += 256) {
    float v = bf2f(row[j]);
    sv[j] = v;
    lm = fmaxf(lm, v);
  }
  float m = bmax(lm, red);
  float ls = 0.f;
  for (int j = threadIdx.x; j < nv; j += 256) {
    float e = expf(sv[j] - m);
    sv[j] = e;
    ls += e;
  }
  float inv = 1.f / bsum(ls, red);
  for (int j = threadIdx.x; j < nv; j += 256) row[j] = f2bf(sv[j] * inv);
  int nfill = (i / 64 + 1) * 64;
  for (int j = nv + threadIdx.x; j < nfill; j += 256) row[j] = 0;
}

// ---------------- PV: y = probs @ v ----------------
__global__ void k_pv(const u16* __restrict__ pr, const u16* __restrict__ vT,
                     u16* __restrict__ yb) {
  int ti = blockIdx.x, bh = blockIdx.y;
  __shared__ u16 Ps[64 * 72];
  __shared__ u16 Vs[64 * 72];
  int tid = threadIdx.x;
  int rr = tid >> 2, cc = tid & 3;
  int wid = tid >> 6, lane = tid & 63;
  int rl = lane & 15, g = lane >> 4;
  f32x4 acc[4] = {};
  const u16* gp = pr + ((size_t)bh * SEQ + ti * 64 + rr) * SEQ;
  const u16* gv = vT + ((size_t)bh * HD2 + rr) * SEQ;
  for (int kt = 0; kt <= ti; ++kt) {
    __syncthreads();
    *(uint4*)&Ps[rr * 72 + cc * 8]      = *(const uint4*)(gp + kt * 64 + cc * 8);
    *(uint4*)&Ps[rr * 72 + cc * 8 + 32] = *(const uint4*)(gp + kt * 64 + cc * 8 + 32);
    *(uint4*)&Vs[rr * 72 + cc * 8]      = *(const uint4*)(gv + kt * 64 + cc * 8);
    *(uint4*)&Vs[rr * 72 + cc * 8 + 32] = *(const uint4*)(gv + kt * 64 + cc * 8 + 32);
    __syncthreads();
#pragma unroll
    for (int ks = 0; ks < 2; ++ks) {
      bf16x8 a = *(const bf16x8*)&Ps[(wid * 16 + rl) * 72 + ks * 32 + g * 8];
#pragma unroll
      for (int nt = 0; nt < 4; ++nt) {
        bf16x8 bb = *(const bf16x8*)&Vs[(nt * 16 + rl) * 72 + ks * 32 + g * 8];
        acc[nt] = __builtin_amdgcn_mfma_f32_16x16x32_bf16(a, bb, acc[nt], 0, 0, 0);
      }
    }
  }
  int b = bh / NH, h = bh % NH;
#pragma unroll
  for (int nt = 0; nt < 4; ++nt) {
    int d = nt * 16 + rl;
#pragma unroll
    for (int r2 = 0; r2 < 4; ++r2) {
      int trow = ti * 64 + wid * 16 + g * 4 + r2;
      yb[((size_t)(b * SEQ + trow)) * DM + h * HD2 + d] = f2bf(acc[nt][r2]);
    }
  }
}

// ---------------- logits GEMM: C[M,N]f32 = A[M,K]bf16 * Bt[N,K]bf16 ---------
// 128x128 tile, BK=32, source-preswizzled LDS (2-way conflict-free reads),
// LDS-staged coalesced f32 epilogue.
__global__ void k_logits(const u16* __restrict__ A, const u16* __restrict__ Bt,
                         float* __restrict__ outf, int M, int N, int K, int MT) {
  __shared__ u16 SM[8448];  // As[4096] | Bs[4096]; aliased as f32 cw[32][132]
  u16* As = SM;
  u16* Bs = SM + 4096;
  float* cw = (float*)SM;
  int nwg = gridDim.x;
  int id = blockIdx.x;
  if ((nwg & 7) == 0) id = (id & 7) * (nwg >> 3) + (id >> 3);  // XCD swizzle
  int mt = id % MT, nt = id / MT;
  int m0 = mt * 128, n0 = nt * 128;
  int tid = threadIdx.x;
  int w = tid >> 6, l = tid & 63;
  // staging: chunk idx (c*256+tid); row = idx>>2, slot = idx&3, swizzled source
  int row0 = tid >> 2, slot0 = tid & 3;
  int gs0 = slot0 ^ ((row0 >> 1) & 3);   // (row+64)>>1 &3 is identical
  const u16* gA0 = A + (size_t)(m0 + row0) * K + gs0 * 8;
  const u16* gA1 = gA0 + (size_t)64 * K;
  int nr0 = n0 + row0;      if (nr0 > N - 1) nr0 = N - 1;
  int nr1 = n0 + row0 + 64; if (nr1 > N - 1) nr1 = N - 1;
  const u16* gB0 = Bt + (size_t)nr0 * K + gs0 * 8;
  const u16* gB1 = Bt + (size_t)nr1 * K + gs0 * 8;
  u16* dA0 = As + w * 512;
  u16* dA1 = As + 2048 + w * 512;
  u16* dB0 = Bs + w * 512;
  u16* dB1 = Bs + 2048 + w * 512;
  int wm = (w >> 1) * 64, wn = (w & 1) * 64;
  int rl = l & 15, g = l >> 4;
  int sla = g ^ ((rl >> 1) & 3);  // read-side swizzle (lane-constant)
  f32x4 acc[4][4] = {};
  int nK = K >> 5;
  for (int kt = 0; kt < nK; ++kt) {
    __syncthreads();
    glds16(gA0 + kt * 32, dA0);
    glds16(gA1 + kt * 32, dA1);
    glds16(gB0 + kt * 32, dB0);
    glds16(gB1 + kt * 32, dB1);
    __syncthreads();
    bf16x8 af[4], bfr[4];
#pragma unroll
    for (int i = 0; i < 4; ++i)
      af[i] = *(const bf16x8*)&As[(wm + i * 16 + rl) * 32 + sla * 8];
#pragma unroll
    for (int i = 0; i < 4; ++i)
      bfr[i] = *(const bf16x8*)&Bs[(wn + i * 16 + rl) * 32 + sla * 8];
#pragma unroll
    for (int i = 0; i < 4; ++i)
#pragma unroll
      for (int j = 0; j < 4; ++j)
        acc[i][j] = __builtin_amdgcn_mfma_f32_16x16x32_bf16(af[i], bfr[j],
                                                            acc[i][j], 0, 0, 0);
  }
  // epilogue: 32-row chunks through LDS, coalesced f32 row writes
  for (int ch = 0; ch < 4; ++ch) {
    __syncthreads();
    if ((w >> 1) == (ch >> 1)) {
      int ib = (ch & 1) * 2;
#pragma unroll
      for (int ii = 0; ii < 2; ++ii) {
#pragma unroll
        for (int j = 0; j < 4; ++j) {
          int col = wn + j * 16 + rl;
#pragma unroll
          for (int r2 = 0; r2 < 4; ++r2) {
            int rowc = ii * 16 + g * 4 + r2;
            cw[rowc * 132 + col] = acc[ib + ii][j][r2];
          }
        }
      }
    }
    __syncthreads();
    for (int t = tid; t < 4096; t += 256) {
      int rowc = t >> 7, col = t & 127;
      int gc = n0 + col;
      if (gc < N) outf[(size_t)(m0 + ch * 32 + rowc) * N + gc] = cw[rowc * 132 + col];
    }
  }
}

// ---------------- 64x64-tile GEMM (occupancy kernel), BK=64, split-K --------
// modes: 0 bf16 out; 1 bf16 gelu out; 2 f32 atomic residual add (+bias at sk0)
__global__ void k_gemm64(const u16* __restrict__ A, const u16* __restrict__ Bt,
                         const float* __restrict__ bias, u16* __restrict__ outb,
                         float* __restrict__ outf, int M, int N, int K, int MT,
                         int mode) {
  __shared__ u16 As[4096];
  __shared__ u16 Bs[4096];
  int nwg = gridDim.x;
  int id = blockIdx.x;
  if ((nwg & 7) == 0) id = (id & 7) * (nwg >> 3) + (id >> 3);  // XCD swizzle
  int mt = id % MT, nt = id / MT;
  int sk = blockIdx.y, nsk = gridDim.y;
  int Kc = K / nsk, k0 = sk * Kc;
  int m0 = mt * 64, n0 = nt * 64;
  int tid = threadIdx.x;
  int w = tid >> 6, l = tid & 63;
  // staging: chunk idx (c*256+tid); row = idx>>3 (0..63), slot = idx&7
  int row0 = tid >> 3, slot0 = tid & 7;
  int gs0 = slot0 ^ (row0 & 7);          // (row+32)&7 identical
  const u16* gA0 = A + (size_t)(m0 + row0) * K + k0 + gs0 * 8;
  const u16* gA1 = gA0 + (size_t)32 * K;
  const u16* gB0 = Bt + (size_t)(n0 + row0) * K + k0 + gs0 * 8;
  const u16* gB1 = gB0 + (size_t)32 * K;
  u16* dA0 = As + w * 512;
  u16* dA1 = As + 2048 + w * 512;
  u16* dB0 = Bs + w * 512;
  u16* dB1 = Bs + 2048 + w * 512;
  int wm = (w >> 1) * 32, wn = (w & 1) * 32;
  int rl = l & 15, g = l >> 4;
  int sl0 = g ^ (rl & 7), sl1 = (4 + g) ^ (rl & 7);  // k-slice 0/1 read swizzle
  f32x4 acc[2][2] = {};
  int nK = Kc >> 6;
  for (int kt = 0; kt < nK; ++kt) {
    __syncthreads();
    glds16(gA0 + kt * 64, dA0);
    glds16(gA1 + kt * 64, dA1);
    glds16(gB0 + kt * 64, dB0);
    glds16(gB1 + kt * 64, dB1);
    __syncthreads();
    bf16x8 a0[2], a1[2], b0[2], b1[2];
#pragma unroll
    for (int i = 0; i < 2; ++i) {
      int r = (wm + i * 16 + rl) * 64;
      a0[i] = *(const bf16x8*)&As[r + sl0 * 8];
      a1[i] = *(const bf16x8*)&As[r + sl1 * 8];
    }
#pragma unroll
    for (int j = 0; j < 2; ++j) {
      int r = (wn + j * 16 + rl) * 64;
      b0[j] = *(const bf16x8*)&Bs[r + sl0 * 8];
      b1[j] = *(const bf16x8*)&Bs[r + sl1 * 8];
    }
#pragma unroll
    for (int i = 0; i < 2; ++i)
#pragma unroll
      for (int j = 0; j < 2; ++j) {
        acc[i][j] = __builtin_amdgcn_mfma_f32_16x16x32_bf16(a0[i], b0[j],
                                                            acc[i][j], 0, 0, 0);
        acc[i][j] = __builtin_amdgcn_mfma_f32_16x16x32_bf16(a1[i], b1[j],
                                                            acc[i][j], 0, 0, 0);
      }
  }
#pragma unroll
  for (int i = 0; i < 2; ++i) {
#pragma unroll
    for (int j = 0; j < 2; ++j) {
      int col = n0 + wn + j * 16 + rl;
      float bv = bias ? bias[col] : 0.f;
#pragma unroll
      for (int r2 = 0; r2 < 4; ++r2) {
        int row = m0 + wm + i * 16 + g * 4 + r2;
        size_t oi = (size_t)row * N + col;
        float v = acc[i][j][r2];
        if (mode == 0) {
          outb[oi] = f2bf(v + bv);
        } else if (mode == 1) {
          v += bv;
          float u = 0.7978845608028654f * (v + 0.044715f * v * v * v);
          outb[oi] = f2bf(0.5f * v * (1.f + tanhf(u)));
        } else {
          if (sk == 0) v += bv;
          atomicAdd(&outf[oi], v);
        }
      }
    }
  }
}

// ---------------- fallback GEMM (f32 B, on-the-fly cvt) — logits only --------
__global__ void k_gemm_f32b(const u16* __restrict__ A, const float* __restrict__ B,
                            float* __restrict__ outf, int M, int N, int K) {
  __shared__ u16 As[128 * 40];
  __shared__ u16 Bs[4 * 128 * 12];
  int tid = threadIdx.x;
  int wid = tid >> 6, lane = tid & 63;
  int rl = lane & 15, g = lane >> 4;
  int m0 = blockIdx.x * 128, n0 = blockIdx.y * 128;
  int wm = (wid >> 1) * 64, wn = (wid & 1) * 64;
  int ar = tid >> 2, ac = tid & 3;
  int bn = tid & 127, bq = tid >> 7;
  f32x4 acc[4][4] = {};
  int nK = K / 32;
  for (int kt = 0; kt < nK; ++kt) {
    __syncthreads();
    {
      const u16* ga = A + (size_t)(m0 + ar) * K + kt * 32 + ac * 8;
      *(uint4*)&As[ar * 40 + ac * 8] = *(const uint4*)ga;
      *(uint4*)&As[(ar + 64) * 40 + ac * 8] = *(const uint4*)(ga + (size_t)64 * K);
    }
    int col = n0 + bn;
#pragma unroll
    for (int r = 0; r < 4; ++r) {
      int kq = bq + 2 * r;
      int kk = kt * 32 + kq * 4;
      float f0 = 0.f, f1 = 0.f, f2v = 0.f, f3 = 0.f;
      if (col < N) {
        const float* gb = B + (size_t)kk * N + col;
        f0 = gb[0]; f1 = gb[(size_t)N]; f2v = gb[(size_t)2 * N]; f3 = gb[(size_t)3 * N];
      }
      uint2 wv;
      wv.x = (u32)f2bf(f0) | ((u32)f2bf(f1) << 16);
      wv.y = (u32)f2bf(f2v) | ((u32)f2bf(f3) << 16);
      *(uint2*)&Bs[(kq >> 1) * 1536 + bn * 12 + (kq & 1) * 4] = wv;
    }
    __syncthreads();
    bf16x8 af[4], bfr[4];
#pragma unroll
    for (int mt = 0; mt < 4; ++mt)
      af[mt] = *(const bf16x8*)&As[(wm + mt * 16 + rl) * 40 + g * 8];
#pragma unroll
    for (int nt = 0; nt < 4; ++nt) {
      const u16* p = &Bs[g * 1536 + (wn + nt * 16 + rl) * 12];
      union { bf16x8 v; uint2 u2[2]; } tmp;
      tmp.u2[0] = *(const uint2*)p;
      tmp.u2[1] = *(const uint2*)(p + 4);
      bfr[nt] = tmp.v;
    }
#pragma unroll
    for (int mt = 0; mt < 4; ++mt)
#pragma unroll
      for (int nt = 0; nt < 4; ++nt)
        acc[mt][nt] = __builtin_amdgcn_mfma_f32_16x16x32_bf16(af[mt], bfr[nt],
                                                              acc[mt][nt], 0, 0, 0);
  }
#pragma unroll
  for (int mt = 0; mt < 4; ++mt)
#pragma unroll
    for (int nt = 0; nt < 4; ++nt) {
      int col = n0 + wn + nt * 16 + rl;
      if (col >= N) continue;
#pragma unroll
      for (int r2 = 0; r2 < 4; ++r2) {
        int row = m0 + wm + mt * 16 + g * 4 + r2;
        outf[(size_t)row * N + col] = acc[mt][nt][r2];
      }
    }
}

extern "C" void kernel_launch(void* const* d_in, const int* in_sizes, int n_in,
                              void* d_out, int out_size, void* d_ws, size_t ws_size,
                              hipStream_t stream) {
  (void)in_sizes; (void)n_in; (void)out_size;
  const int*   idx  = (const int*)  d_in[0];
  const float* wte  = (const float*)d_in[1];
  const float* ln1g = (const float*)d_in[2];
  const float* ln1b = (const float*)d_in[3];
  const float* Wqkv = (const float*)d_in[4];
  const float* bqkv = (const float*)d_in[5];
  const float* Wo   = (const float*)d_in[6];
  const float* bo   = (const float*)d_in[7];
  const float* ln2g = (const float*)d_in[8];
  const float* ln2b = (const float*)d_in[9];
  const float* Wfc  = (const float*)d_in[10];
  const float* bfc  = (const float*)d_in[11];
  const float* Wp   = (const float*)d_in[12];
  const float* bp   = (const float*)d_in[13];
  const float* lnfg = (const float*)d_in[14];
  const float* lnfb = (const float*)d_in[15];
  const float* Wlm  = (const float*)d_in[16];
  float* out = (float*)d_out;

  // Scratch packed into d_out (all dead before the logits GEMM rewrites d_out).
  char* sb = (char*)d_out;
  size_t off = 0;
  auto alloc = [&](size_t bytes) {
    char* p = sb + off;
    off += (bytes + 255) & ~(size_t)255;
    return (void*)p;
  };
  float* xf  = (float*)alloc((size_t)BT * DM * 4);
  u16* h1b   = (u16*)alloc((size_t)BT * DM * 2);
  u16* h2b   = (u16*)alloc((size_t)BT * DM * 2);
  u16* qkvb  = (u16*)alloc((size_t)BT * 3 * DM * 2);
  u16* qr    = (u16*)alloc((size_t)BT * DM * 2);
  u16* kr    = (u16*)alloc((size_t)BT * DM * 2);
  u16* vT    = (u16*)alloc((size_t)BT * DM * 2);
  u16* sc    = (u16*)alloc((size_t)2 * NH * SEQ * SEQ * 2);
  u16* yb    = (u16*)alloc((size_t)BT * DM * 2);
  u16* hgel  = (u16*)alloc((size_t)BT * 4 * DM * 2);
  // transposed bf16 weights (also dead before logits GEMM)
  u16* wqkvT = (u16*)alloc((size_t)NLAYER * 3 * DM * DM * 2);
  u16* woT   = (u16*)alloc((size_t)NLAYER * DM * DM * 2);
  u16* wfcT  = (u16*)alloc((size_t)NLAYER * 4 * DM * DM * 2);
  u16* wpT   = (u16*)alloc((size_t)NLAYER * 4 * DM * DM * 2);

  // Wlm^T (77 MB) must survive the logits GEMM -> d_ws if it fits.
  size_t wlmT_bytes = (size_t)NVOCAB * DM * 2;
  size_t xlnf_bytes = (size_t)BT * DM * 2;
  bool fast_lm = ws_size >= wlmT_bytes + xlnf_bytes + 512;
  u16* wlmT = (u16*)d_ws;
  u16* xlnf = fast_lm ? (u16*)((char*)d_ws + ((wlmT_bytes + 255) & ~(size_t)255))
                      : (u16*)d_ws;

  // ---- weight conversion pass ----
  for (int l = 0; l < NLAYER; ++l) {
    k_cvtT<<<dim3((3 * DM + 31) / 32, DM / 32), 256, 0, stream>>>(
        Wqkv + (size_t)l * DM * 3 * DM, wqkvT + (size_t)l * 3 * DM * DM, DM, 3 * DM);
    k_cvtT<<<dim3(DM / 32, DM / 32), 256, 0, stream>>>(
        Wo + (size_t)l * DM * DM, woT + (size_t)l * DM * DM, DM, DM);
    k_cvtT<<<dim3((4 * DM) / 32, DM / 32), 256, 0, stream>>>(
        Wfc + (size_t)l * DM * 4 * DM, wfcT + (size_t)l * 4 * DM * DM, DM, 4 * DM);
    k_cvtT<<<dim3(DM / 32, (4 * DM) / 32), 256, 0, stream>>>(
        Wp + (size_t)l * 4 * DM * DM, wpT + (size_t)l * 4 * DM * DM, 4 * DM, DM);
  }
  if (fast_lm)
    k_cvtT<<<dim3((NVOCAB + 31) / 32, DM / 32), 256, 0, stream>>>(Wlm, wlmT, DM, NVOCAB);

  k_embed<<<BT, 256, 0, stream>>>(idx, wte, xf);
  for (int l = 0; l < NLAYER; ++l) {
    k_ln<<<BT, 256, 0, stream>>>(xf, ln1g + l * DM, ln1b + l * DM,
                                 ln2g + l * DM, ln2b + l * DM, h1b, h2b);
    k_gemm64<<<dim3((BT / 64) * (3 * DM / 64), 1), 256, 0, stream>>>(
        h1b, wqkvT + (size_t)l * 3 * DM * DM, bqkv + (size_t)l * 3 * DM,
        qkvb, nullptr, BT, 3 * DM, DM, BT / 64, 0);
    k_rope<<<(2 * SEQ * NH * 32) / 256, 256, 0, stream>>>(qkvb, qr, kr);
    k_vtrans<<<dim3(SEQ / 64, 2 * NH), 256, 0, stream>>>(qkvb, vT);
    k_qk<<<dim3(16, 16, 2 * NH), 256, 0, stream>>>(qr, kr, sc);
    k_softmax<<<dim3(SEQ, 2 * NH), 256, 0, stream>>>(sc);
    k_pv<<<dim3(16, 2 * NH), 256, 0, stream>>>(sc, vT, yb);
    k_gemm64<<<dim3((BT / 64) * (DM / 64), 2), 256, 0, stream>>>(
        yb, woT + (size_t)l * DM * DM, bo + (size_t)l * DM,
        nullptr, xf, BT, DM, DM, BT / 64, 2);
    k_gemm64<<<dim3((BT / 64) * (4 * DM / 64), 1), 256, 0, stream>>>(
        h2b, wfcT + (size_t)l * 4 * DM * DM, bfc + (size_t)l * 4 * DM,
        hgel, nullptr, BT, 4 * DM, DM, BT / 64, 1);
    k_gemm64<<<dim3((BT / 64) * (DM / 64), 4), 256, 0, stream>>>(
        hgel, wpT + (size_t)l * 4 * DM * DM, bp + (size_t)l * DM,
        nullptr, xf, BT, DM, 4 * DM, BT / 64, 2);
  }
  k_ln<<<BT, 256, 0, stream>>>(xf, lnfg, lnfb, nullptr, nullptr, xlnf, nullptr);
  if (fast_lm) {
    int nt = (NVOCAB + 127) / 128;
    k_logits<<<(BT / 128) * nt, 256, 0, stream>>>(
        xlnf, wlmT, out, BT, NVOCAB, DM, BT / 128);
  } else {
    k_gemm_f32b<<<dim3(BT / 128, (NVOCAB + 127) / 128), 256, 0, stream>>>(
        xlnf, Wlm, out, BT, NVOCAB, DM);
  }
}

// Round 4
// 1020.498 us; speedup vs baseline: 2.8873x; 1.0786x over previous
//
#include <hip/hip_runtime.h>

typedef unsigned short u16;
typedef unsigned int u32;
typedef __attribute__((ext_vector_type(8))) short bf16x8;
typedef __attribute__((ext_vector_type(4))) float f32x4;

#define SEQ 1024
#define DM 768
#define NH 12
#define HD2 64
#define NLAYER 4
#define NVOCAB 50257
#define BT 2048  // B*T

__device__ __forceinline__ u16 f2bf(float f) {
  union { float f; u32 u; } v; v.f = f;
  u32 r = v.u + 0x7FFFu + ((v.u >> 16) & 1u);
  return (u16)(r >> 16);
}
__device__ __forceinline__ float bf2f(u16 u) {
  union { u32 u; float f; } v; v.u = ((u32)u) << 16;
  return v.f;
}

__device__ __forceinline__ void glds16(const u16* g, u16* l) {
  __builtin_amdgcn_global_load_lds(
      (const __attribute__((address_space(1))) u32*)(const void*)g,
      (__attribute__((address_space(3))) u32*)(void*)l, 16, 0, 0);
}

// ---------------- embedding ----------------
__global__ void k_embed(const int* __restrict__ idx, const float* __restrict__ wte,
                        float* __restrict__ xf) {
  int r = blockIdx.x;
  int tok = idx[r];
  const float* s = wte + (size_t)tok * DM;
  float* d = xf + (size_t)r * DM;
  for (int c = threadIdx.x; c < DM; c += 256) d[c] = s[c];
}

// ---------------- transpose + f32->bf16: in[R,C] f32 -> out[C,R] bf16 -------
__global__ void k_cvtT(const float* __restrict__ in, u16* __restrict__ out,
                       int R, int C) {
  __shared__ u16 t[32][34];
  int c0 = blockIdx.x * 32, r0 = blockIdx.y * 32;
  int tx = threadIdx.x & 31, ty = threadIdx.x >> 5;  // ty in 0..7
#pragma unroll
  for (int i = 0; i < 4; ++i) {
    int r = r0 + ty + i * 8, c = c0 + tx;
    float v = (c < C) ? in[(size_t)r * C + c] : 0.f;  // R always multiple of 32
    t[ty + i * 8][tx] = f2bf(v);
  }
  __syncthreads();
  // packed u32 stores: 2 consecutive rows per thread
  int cy = threadIdx.x >> 4;        // 0..15
  int rx = (threadIdx.x & 15) * 2;  // 0,2,..30
#pragma unroll
  for (int i = 0; i < 2; ++i) {
    int c = c0 + cy + i * 16;
    if (c < C) {
      u32 wv = (u32)t[rx][cy + i * 16] | ((u32)t[rx + 1][cy + i * 16] << 16);
      *(u32*)&out[(size_t)c * R + r0 + rx] = wv;
    }
  }
}

// ---------------- block reductions (256 thr = 4 waves) ----------------
__device__ __forceinline__ float bsum(float v, float* red) {
#pragma unroll
  for (int o = 32; o > 0; o >>= 1) v += __shfl_down(v, o);
  if ((threadIdx.x & 63) == 0) red[threadIdx.x >> 6] = v;
  __syncthreads();
  if (threadIdx.x == 0) red[4] = red[0] + red[1] + red[2] + red[3];
  __syncthreads();
  return red[4];
}

// ---------------- dual layernorm (both read same x) ----------------
__global__ void k_ln(const float* __restrict__ x, const float* __restrict__ g1,
                     const float* __restrict__ b1, const float* __restrict__ g2,
                     const float* __restrict__ b2, u16* __restrict__ o1,
                     u16* __restrict__ o2) {
  __shared__ float red[8];
  int r = blockIdx.x;
  int t = threadIdx.x;
  const float* xr = x + (size_t)r * DM;
  float v0 = xr[t], v1 = xr[t + 256], v2 = xr[t + 512];
  float mean = bsum(v0 + v1 + v2, red) * (1.f / DM);
  float d0 = v0 - mean, d1 = v1 - mean, d2 = v2 - mean;
  float var = bsum(d0 * d0 + d1 * d1 + d2 * d2, red) * (1.f / DM);
  float rstd = rsqrtf(var + 1e-5f);
  u16* p1 = o1 + (size_t)r * DM;
  p1[t]       = f2bf(d0 * rstd * g1[t]       + b1[t]);
  p1[t + 256] = f2bf(d1 * rstd * g1[t + 256] + b1[t + 256]);
  p1[t + 512] = f2bf(d2 * rstd * g1[t + 512] + b1[t + 512]);
  if (o2) {
    u16* p2 = o2 + (size_t)r * DM;
    p2[t]       = f2bf(d0 * rstd * g2[t]       + b2[t]);
    p2[t + 256] = f2bf(d1 * rstd * g2[t + 256] + b2[t + 256]);
    p2[t + 512] = f2bf(d2 * rstd * g2[t + 512] + b2[t + 512]);
  }
}

// ---------------- partial RoPE on q,k ----------------
__global__ void k_rope(const u16* __restrict__ qkvb, u16* __restrict__ qr,
                       u16* __restrict__ kr) {
  int gid = blockIdx.x * 256 + threadIdx.x;  // over B*T*NH*32
  int j = gid & 31;
  int h = (gid >> 5) % NH;
  int t = (gid / (32 * NH)) & (SEQ - 1);
  int b = gid / (32 * NH * SEQ);
  float c = 1.f, s = 0.f;
  if (j < 16) {
    float inv = powf(10000.f, -(float)j * (1.f / 32.f));
    float ang = (float)t * inv;
    c = cosf(ang);
    s = sinf(ang);
  }
  size_t base = (size_t)(b * SEQ + t) * (3 * DM);
  size_t ob = ((size_t)(b * NH + h) * SEQ + t) * HD2 + j;
  {
    float a0 = bf2f(qkvb[base + h * HD2 + j]);
    float a1 = bf2f(qkvb[base + h * HD2 + j + 32]);
    qr[ob] = f2bf(a0 * c - a1 * s);
    qr[ob + 32] = f2bf(a1 * c + a0 * s);
  }
  {
    float a0 = bf2f(qkvb[base + DM + h * HD2 + j]);
    float a1 = bf2f(qkvb[base + DM + h * HD2 + j + 32]);
    kr[ob] = f2bf(a0 * c - a1 * s);
    kr[ob + 32] = f2bf(a1 * c + a0 * s);
  }
}

// ---------------- v transpose: [B,T,H,HD] slice -> [B,H,HD,T] ----------------
__global__ void k_vtrans(const u16* __restrict__ qkvb, u16* __restrict__ vT) {
  __shared__ u16 tile[64][65];
  int t0 = blockIdx.x * 64;
  int bh = blockIdx.y;
  int b = bh / NH, h = bh % NH;
  int rr = threadIdx.x >> 2, seg = threadIdx.x & 3;
  const u16* src = qkvb + (size_t)(b * SEQ + t0 + rr) * (3 * DM) + 2 * DM + h * HD2;
#pragma unroll
  for (int i = 0; i < 16; ++i) tile[rr][seg * 16 + i] = src[seg * 16 + i];
  __syncthreads();
  u16* dst = vT + ((size_t)bh * HD2 + rr) * SEQ + t0;
#pragma unroll
  for (int i = 0; i < 16; ++i) dst[seg * 16 + i] = tile[seg * 16 + i][rr];
}

// ---------------- fused flash attention: one block = 64 q-rows of one head --
// Q,K from roped buffers [bh][t][d]; V^T from vT [bh][d][t]; out into yb.
__global__ void k_attn(const u16* __restrict__ qr, const u16* __restrict__ kr,
                       const u16* __restrict__ vT, u16* __restrict__ yb) {
  int ti = (int)gridDim.x - 1 - (int)blockIdx.x;  // big tiles first
  int bh = blockIdx.y;
  __shared__ u16 Ps[64 * 72];  // Q staging, then P tile
  __shared__ u16 Ks[64 * 72];
  __shared__ u16 Vs[64 * 72];
  int tid = threadIdx.x;
  int rr = tid >> 2, cc = tid & 3;
  int w = tid >> 6, l = tid & 63;
  int rl = l & 15, g = l >> 4;
  // stage Q tile, hoist A-fragments to regs, then reuse Ps for P
  {
    const u16* gq = qr + ((size_t)bh * SEQ + ti * 64 + rr) * HD2;
    *(uint4*)&Ps[rr * 72 + cc * 8]      = *(const uint4*)(gq + cc * 8);
    *(uint4*)&Ps[rr * 72 + cc * 8 + 32] = *(const uint4*)(gq + cc * 8 + 32);
  }
  __syncthreads();
  bf16x8 aq0 = *(const bf16x8*)&Ps[(w * 16 + rl) * 72 + g * 8];
  bf16x8 aq1 = *(const bf16x8*)&Ps[(w * 16 + rl) * 72 + 32 + g * 8];
  float m[4], lsum[4];
  f32x4 oacc[4] = {};
#pragma unroll
  for (int r2 = 0; r2 < 4; ++r2) { m[r2] = -3.0e38f; lsum[r2] = 0.f; }
  const u16* gk = kr + ((size_t)bh * SEQ + rr) * HD2;
  const u16* gv = vT + ((size_t)bh * HD2 + rr) * SEQ;
  int qloc = w * 16 + g * 4;
  for (int kt = 0; kt <= ti; ++kt) {
    __syncthreads();  // prior Ps/Ks/Vs consumers done
    {
      const u16* gkk = gk + (size_t)kt * 64 * HD2;
      *(uint4*)&Ks[rr * 72 + cc * 8]      = *(const uint4*)(gkk + cc * 8);
      *(uint4*)&Ks[rr * 72 + cc * 8 + 32] = *(const uint4*)(gkk + cc * 8 + 32);
      *(uint4*)&Vs[rr * 72 + cc * 8]      = *(const uint4*)(gv + kt * 64 + cc * 8);
      *(uint4*)&Vs[rr * 72 + cc * 8 + 32] = *(const uint4*)(gv + kt * 64 + cc * 8 + 32);
    }
    __syncthreads();
    f32x4 s[4] = {};
#pragma unroll
    for (int nt = 0; nt < 4; ++nt) {
      bf16x8 b0 = *(const bf16x8*)&Ks[(nt * 16 + rl) * 72 + g * 8];
      bf16x8 b1 = *(const bf16x8*)&Ks[(nt * 16 + rl) * 72 + 32 + g * 8];
      s[nt] = __builtin_amdgcn_mfma_f32_16x16x32_bf16(aq0, b0, s[nt], 0, 0, 0);
      s[nt] = __builtin_amdgcn_mfma_f32_16x16x32_bf16(aq1, b1, s[nt], 0, 0, 0);
    }
#pragma unroll
    for (int nt = 0; nt < 4; ++nt) s[nt] *= 0.125f;
    if (kt == ti) {
#pragma unroll
      for (int nt = 0; nt < 4; ++nt) {
        int col = nt * 16 + rl;
#pragma unroll
        for (int r2 = 0; r2 < 4; ++r2)
          if (col > qloc + r2) s[nt][r2] = -3.0e38f;
      }
    }
    // online softmax per owned q-row (r2); cols spread over nt x rl(16 lanes)
#pragma unroll
    for (int r2 = 0; r2 < 4; ++r2) {
      float pm = fmaxf(fmaxf(s[0][r2], s[1][r2]), fmaxf(s[2][r2], s[3][r2]));
#pragma unroll
      for (int o = 1; o < 16; o <<= 1) pm = fmaxf(pm, __shfl_xor(pm, o));
      float mn = fmaxf(m[r2], pm);
      float corr = __expf(m[r2] - mn);
      float p0 = __expf(s[0][r2] - mn);
      float p1 = __expf(s[1][r2] - mn);
      float p2 = __expf(s[2][r2] - mn);
      float p3 = __expf(s[3][r2] - mn);
      float ps = p0 + p1 + p2 + p3;
#pragma unroll
      for (int o = 1; o < 16; o <<= 1) ps += __shfl_xor(ps, o);
      lsum[r2] = lsum[r2] * corr + ps;
      m[r2] = mn;
      oacc[0][r2] *= corr; oacc[1][r2] *= corr;
      oacc[2][r2] *= corr; oacc[3][r2] *= corr;
      int prow = (qloc + r2) * 72;
      Ps[prow + rl]      = f2bf(p0);
      Ps[prow + 16 + rl] = f2bf(p1);
      Ps[prow + 32 + rl] = f2bf(p2);
      Ps[prow + 48 + rl] = f2bf(p3);
    }
    __syncthreads();  // P complete
    bf16x8 pa0 = *(const bf16x8*)&Ps[(w * 16 + rl) * 72 + g * 8];
    bf16x8 pa1 = *(const bf16x8*)&Ps[(w * 16 + rl) * 72 + 32 + g * 8];
#pragma unroll
    for (int nt = 0; nt < 4; ++nt) {
      bf16x8 b0 = *(const bf16x8*)&Vs[(nt * 16 + rl) * 72 + g * 8];
      bf16x8 b1 = *(const bf16x8*)&Vs[(nt * 16 + rl) * 72 + 32 + g * 8];
      oacc[nt] = __builtin_amdgcn_mfma_f32_16x16x32_bf16(pa0, b0, oacc[nt], 0, 0, 0);
      oacc[nt] = __builtin_amdgcn_mfma_f32_16x16x32_bf16(pa1, b1, oacc[nt], 0, 0, 0);
    }
  }
  int b = bh / NH, h = bh % NH;
  float invl[4];
#pragma unroll
  for (int r2 = 0; r2 < 4; ++r2) invl[r2] = 1.f / lsum[r2];
#pragma unroll
  for (int nt = 0; nt < 4; ++nt) {
    int d = nt * 16 + rl;
#pragma unroll
    for (int r2 = 0; r2 < 4; ++r2) {
      int trow = ti * 64 + qloc + r2;
      yb[((size_t)(b * SEQ + trow)) * DM + h * HD2 + d] = f2bf(oacc[nt][r2] * invl[r2]);
    }
  }
}

// ---------------- logits GEMM: C[M,N]f32 = A[M,K]bf16 * Bt[N,K]bf16 ---------
// 128x128 tile, BK=64, source-preswizzled LDS, LDS-staged coalesced f32 epilogue
__global__ void k_logits(const u16* __restrict__ A, const u16* __restrict__ Bt,
                         float* __restrict__ outf, int M, int N, int K, int MT) {
  __shared__ u16 SM[16384];  // As[8192] | Bs[8192]; alias f32 cw[32][132]
  u16* As = SM;
  u16* Bs = SM + 8192;
  float* cw = (float*)SM;
  int nwg = gridDim.x;
  int id = blockIdx.x;
  if ((nwg & 7) == 0) id = (id & 7) * (nwg >> 3) + (id >> 3);  // XCD swizzle
  int mt = id % MT, nt = id / MT;
  int m0 = mt * 128, n0 = nt * 128;
  int tid = threadIdx.x;
  int w = tid >> 6, l = tid & 63;
  int rbase = w * 8 + (l >> 3);   // row within each 32-row chunk
  int gs = (l & 7) ^ (l >> 3);    // pre-swizzled source 16B-chunk (lane-const)
  const u16* gA[4];
  const u16* gB[4];
#pragma unroll
  for (int c = 0; c < 4; ++c) {
    gA[c] = A + (size_t)(m0 + c * 32 + rbase) * K + gs * 8;
    int rb = n0 + c * 32 + rbase; if (rb > N - 1) rb = N - 1;
    gB[c] = Bt + (size_t)rb * K + gs * 8;
  }
  u16* dA = As + w * 512;
  u16* dB = Bs + w * 512;
  int wm = (w >> 1) * 64, wn = (w & 1) * 64;
  int rl = l & 15, g = l >> 4;
  int sw = rl & 7;
  f32x4 acc[4][4] = {};
  int nK = K >> 6;
  for (int kt = 0; kt < nK; ++kt) {
    __syncthreads();
#pragma unroll
    for (int c = 0; c < 4; ++c) {
      glds16(gA[c] + kt * 64, dA + c * 2048);
      glds16(gB[c] + kt * 64, dB + c * 2048);
    }
    __syncthreads();
#pragma unroll
    for (int ks = 0; ks < 2; ++ks) {
      bf16x8 af[4], bfr[4];
      int slot = ((ks * 4 + g) ^ sw) * 8;
#pragma unroll
      for (int i = 0; i < 4; ++i)
        af[i] = *(const bf16x8*)&As[(wm + i * 16 + rl) * 64 + slot];
#pragma unroll
      for (int j = 0; j < 4; ++j)
        bfr[j] = *(const bf16x8*)&Bs[(wn + j * 16 + rl) * 64 + slot];
#pragma unroll
      for (int i = 0; i < 4; ++i)
#pragma unroll
        for (int j = 0; j < 4; ++j)
          acc[i][j] = __builtin_amdgcn_mfma_f32_16x16x32_bf16(af[i], bfr[j],
                                                              acc[i][j], 0, 0, 0);
    }
  }
  // epilogue: 32-row chunks through LDS, coalesced f32 row writes
  for (int ch = 0; ch < 4; ++ch) {
    __syncthreads();
    if ((w >> 1) == (ch >> 1)) {
      int ib = (ch & 1) * 2;
#pragma unroll
      for (int ii = 0; ii < 2; ++ii) {
#pragma unroll
        for (int j = 0; j < 4; ++j) {
          int col = wn + j * 16 + rl;
#pragma unroll
          for (int r2 = 0; r2 < 4; ++r2) {
            int rowc = ii * 16 + g * 4 + r2;
            cw[rowc * 132 + col] = acc[ib + ii][j][r2];
          }
        }
      }
    }
    __syncthreads();
    for (int t = tid; t < 4096; t += 256) {
      int rowc = t >> 7, col = t & 127;
      int gc = n0 + col;
      if (gc < N) outf[(size_t)(m0 + ch * 32 + rowc) * N + gc] = cw[rowc * 132 + col];
    }
  }
}

// ---------------- 64x64-tile GEMM (occupancy kernel), BK=64, split-K --------
// modes: 0 bf16 out; 1 bf16 gelu out; 2 f32 atomic residual add (+bias at sk0)
__global__ void k_gemm64(const u16* __restrict__ A, const u16* __restrict__ Bt,
                         const float* __restrict__ bias, u16* __restrict__ outb,
                         float* __restrict__ outf, int M, int N, int K, int MT,
                         int mode) {
  __shared__ u16 As[4096];
  __shared__ u16 Bs[4096];
  int nwg = gridDim.x;
  int id = blockIdx.x;
  if ((nwg & 7) == 0) id = (id & 7) * (nwg >> 3) + (id >> 3);  // XCD swizzle
  int mt = id % MT, nt = id / MT;
  int sk = blockIdx.y, nsk = gridDim.y;
  int Kc = K / nsk, k0 = sk * Kc;
  int m0 = mt * 64, n0 = nt * 64;
  int tid = threadIdx.x;
  int w = tid >> 6, l = tid & 63;
  int row0 = tid >> 3, slot0 = tid & 7;
  int gs0 = slot0 ^ (row0 & 7);
  const u16* gA0 = A + (size_t)(m0 + row0) * K + k0 + gs0 * 8;
  const u16* gA1 = gA0 + (size_t)32 * K;
  const u16* gB0 = Bt + (size_t)(n0 + row0) * K + k0 + gs0 * 8;
  const u16* gB1 = gB0 + (size_t)32 * K;
  u16* dA0 = As + w * 512;
  u16* dA1 = As + 2048 + w * 512;
  u16* dB0 = Bs + w * 512;
  u16* dB1 = Bs + 2048 + w * 512;
  int wm = (w >> 1) * 32, wn = (w & 1) * 32;
  int rl = l & 15, g = l >> 4;
  int sl0 = g ^ (rl & 7), sl1 = (4 + g) ^ (rl & 7);
  f32x4 acc[2][2] = {};
  int nK = Kc >> 6;
  for (int kt = 0; kt < nK; ++kt) {
    __syncthreads();
    glds16(gA0 + kt * 64, dA0);
    glds16(gA1 + kt * 64, dA1);
    glds16(gB0 + kt * 64, dB0);
    glds16(gB1 + kt * 64, dB1);
    __syncthreads();
    bf16x8 a0[2], a1[2], b0[2], b1[2];
#pragma unroll
    for (int i = 0; i < 2; ++i) {
      int r = (wm + i * 16 + rl) * 64;
      a0[i] = *(const bf16x8*)&As[r + sl0 * 8];
      a1[i] = *(const bf16x8*)&As[r + sl1 * 8];
    }
#pragma unroll
    for (int j = 0; j < 2; ++j) {
      int r = (wn + j * 16 + rl) * 64;
      b0[j] = *(const bf16x8*)&Bs[r + sl0 * 8];
      b1[j] = *(const bf16x8*)&Bs[r + sl1 * 8];
    }
#pragma unroll
    for (int i = 0; i < 2; ++i)
#pragma unroll
      for (int j = 0; j < 2; ++j) {
        acc[i][j] = __builtin_amdgcn_mfma_f32_16x16x32_bf16(a0[i], b0[j],
                                                            acc[i][j], 0, 0, 0);
        acc[i][j] = __builtin_amdgcn_mfma_f32_16x16x32_bf16(a1[i], b1[j],
                                                            acc[i][j], 0, 0, 0);
      }
  }
#pragma unroll
  for (int i = 0; i < 2; ++i) {
#pragma unroll
    for (int j = 0; j < 2; ++j) {
      int col = n0 + wn + j * 16 + rl;
      float bv = bias ? bias[col] : 0.f;
#pragma unroll
      for (int r2 = 0; r2 < 4; ++r2) {
        int row = m0 + wm + i * 16 + g * 4 + r2;
        size_t oi = (size_t)row * N + col;
        float v = acc[i][j][r2];
        if (mode == 0) {
          outb[oi] = f2bf(v + bv);
        } else if (mode == 1) {
          v += bv;
          float u = 0.7978845608028654f * (v + 0.044715f * v * v * v);
          outb[oi] = f2bf(0.5f * v * (1.f + tanhf(u)));
        } else {
          if (sk == 0) v += bv;
          atomicAdd(&outf[oi], v);
        }
      }
    }
  }
}

// ---------------- fallback GEMM (f32 B, on-the-fly cvt) — logits only --------
__global__ void k_gemm_f32b(const u16* __restrict__ A, const float* __restrict__ B,
                            float* __restrict__ outf, int M, int N, int K) {
  __shared__ u16 As[128 * 40];
  __shared__ u16 Bs[4 * 128 * 12];
  int tid = threadIdx.x;
  int wid = tid >> 6, lane = tid & 63;
  int rl = lane & 15, g = lane >> 4;
  int m0 = blockIdx.x * 128, n0 = blockIdx.y * 128;
  int wm = (wid >> 1) * 64, wn = (wid & 1) * 64;
  int ar = tid >> 2, ac = tid & 3;
  int bn = tid & 127, bq = tid >> 7;
  f32x4 acc[4][4] = {};
  int nK = K / 32;
  for (int kt = 0; kt < nK; ++kt) {
    __syncthreads();
    {
      const u16* ga = A + (size_t)(m0 + ar) * K + kt * 32 + ac * 8;
      *(uint4*)&As[ar * 40 + ac * 8] = *(const uint4*)ga;
      *(uint4*)&As[(ar + 64) * 40 + ac * 8] = *(const uint4*)(ga + (size_t)64 * K);
    }
    int col = n0 + bn;
#pragma unroll
    for (int r = 0; r < 4; ++r) {
      int kq = bq + 2 * r;
      int kk = kt * 32 + kq * 4;
      float f0 = 0.f, f1 = 0.f, f2v = 0.f, f3 = 0.f;
      if (col < N) {
        const float* gb = B + (size_t)kk * N + col;
        f0 = gb[0]; f1 = gb[(size_t)N]; f2v = gb[(size_t)2 * N]; f3 = gb[(size_t)3 * N];
      }
      uint2 wv;
      wv.x = (u32)f2bf(f0) | ((u32)f2bf(f1) << 16);
      wv.y = (u32)f2bf(f2v) | ((u32)f2bf(f3) << 16);
      *(uint2*)&Bs[(kq >> 1) * 1536 + bn * 12 + (kq & 1) * 4] = wv;
    }
    __syncthreads();
    bf16x8 af[4], bfr[4];
#pragma unroll
    for (int mt = 0; mt < 4; ++mt)
      af[mt] = *(const bf16x8*)&As[(wm + mt * 16 + rl) * 40 + g * 8];
#pragma unroll
    for (int nt = 0; nt < 4; ++nt) {
      const u16* p = &Bs[g * 1536 + (wn + nt * 16 + rl) * 12];
      union { bf16x8 v; uint2 u2[2]; } tmp;
      tmp.u2[0] = *(const uint2*)p;
      tmp.u2[1] = *(const uint2*)(p + 4);
      bfr[nt] = tmp.v;
    }
#pragma unroll
    for (int mt = 0; mt < 4; ++mt)
#pragma unroll
      for (int nt = 0; nt < 4; ++nt)
        acc[mt][nt] = __builtin_amdgcn_mfma_f32_16x16x32_bf16(af[mt], bfr[nt],
                                                              acc[mt][nt], 0, 0, 0);
  }
#pragma unroll
  for (int mt = 0; mt < 4; ++mt)
#pragma unroll
    for (int nt = 0; nt < 4; ++nt) {
      int col = n0 + wn + nt * 16 + rl;
      if (col >= N) continue;
#pragma unroll
      for (int r2 = 0; r2 < 4; ++r2) {
        int row = m0 + wm + mt * 16 + g * 4 + r2;
        outf[(size_t)row * N + col] = acc[mt][nt][r2];
      }
    }
}

extern "C" void kernel_launch(void* const* d_in, const int* in_sizes, int n_in,
                              void* d_out, int out_size, void* d_ws, size_t ws_size,
                              hipStream_t stream) {
  (void)in_sizes; (void)n_in; (void)out_size;
  const int*   idx  = (const int*)  d_in[0];
  const float* wte  = (const float*)d_in[1];
  const float* ln1g = (const float*)d_in[2];
  const float* ln1b = (const float*)d_in[3];
  const float* Wqkv = (const float*)d_in[4];
  const float* bqkv = (const float*)d_in[5];
  const float* Wo   = (const float*)d_in[6];
  const float* bo   = (const float*)d_in[7];
  const float* ln2g = (const float*)d_in[8];
  const float* ln2b = (const float*)d_in[9];
  const float* Wfc  = (const float*)d_in[10];
  const float* bfc  = (const float*)d_in[11];
  const float* Wp   = (const float*)d_in[12];
  const float* bp   = (const float*)d_in[13];
  const float* lnfg = (const float*)d_in[14];
  const float* lnfb = (const float*)d_in[15];
  const float* Wlm  = (const float*)d_in[16];
  float* out = (float*)d_out;

  // Scratch packed into d_out (all dead before the logits GEMM rewrites d_out).
  char* sb = (char*)d_out;
  size_t off = 0;
  auto alloc = [&](size_t bytes) {
    char* p = sb + off;
    off += (bytes + 255) & ~(size_t)255;
    return (void*)p;
  };
  float* xf  = (float*)alloc((size_t)BT * DM * 4);
  u16* h1b   = (u16*)alloc((size_t)BT * DM * 2);
  u16* h2b   = (u16*)alloc((size_t)BT * DM * 2);
  u16* qkvb  = (u16*)alloc((size_t)BT * 3 * DM * 2);
  u16* qr    = (u16*)alloc((size_t)BT * DM * 2);
  u16* kr    = (u16*)alloc((size_t)BT * DM * 2);
  u16* vT    = (u16*)alloc((size_t)BT * DM * 2);
  u16* yb    = (u16*)alloc((size_t)BT * DM * 2);
  u16* hgel  = (u16*)alloc((size_t)BT * 4 * DM * 2);
  // transposed bf16 weights (also dead before logits GEMM)
  u16* wqkvT = (u16*)alloc((size_t)NLAYER * 3 * DM * DM * 2);
  u16* woT   = (u16*)alloc((size_t)NLAYER * DM * DM * 2);
  u16* wfcT  = (u16*)alloc((size_t)NLAYER * 4 * DM * DM * 2);
  u16* wpT   = (u16*)alloc((size_t)NLAYER * 4 * DM * DM * 2);

  // Wlm^T (77 MB) must survive the logits GEMM -> d_ws if it fits.
  size_t wlmT_bytes = (size_t)NVOCAB * DM * 2;
  size_t xlnf_bytes = (size_t)BT * DM * 2;
  bool fast_lm = ws_size >= wlmT_bytes + xlnf_bytes + 512;
  u16* wlmT = (u16*)d_ws;
  u16* xlnf = fast_lm ? (u16*)((char*)d_ws + ((wlmT_bytes + 255) & ~(size_t)255))
                      : (u16*)d_ws;

  // ---- weight conversion pass ----
  for (int l = 0; l < NLAYER; ++l) {
    k_cvtT<<<dim3((3 * DM + 31) / 32, DM / 32), 256, 0, stream>>>(
        Wqkv + (size_t)l * DM * 3 * DM, wqkvT + (size_t)l * 3 * DM * DM, DM, 3 * DM);
    k_cvtT<<<dim3(DM / 32, DM / 32), 256, 0, stream>>>(
        Wo + (size_t)l * DM * DM, woT + (size_t)l * DM * DM, DM, DM);
    k_cvtT<<<dim3((4 * DM) / 32, DM / 32), 256, 0, stream>>>(
        Wfc + (size_t)l * DM * 4 * DM, wfcT + (size_t)l * 4 * DM * DM, DM, 4 * DM);
    k_cvtT<<<dim3(DM / 32, (4 * DM) / 32), 256, 0, stream>>>(
        Wp + (size_t)l * 4 * DM * DM, wpT + (size_t)l * 4 * DM * DM, 4 * DM, DM);
  }
  if (fast_lm)
    k_cvtT<<<dim3((NVOCAB + 31) / 32, DM / 32), 256, 0, stream>>>(Wlm, wlmT, DM, NVOCAB);

  k_embed<<<BT, 256, 0, stream>>>(idx, wte, xf);
  for (int l = 0; l < NLAYER; ++l) {
    k_ln<<<BT, 256, 0, stream>>>(xf, ln1g + l * DM, ln1b + l * DM,
                                 ln2g + l * DM, ln2b + l * DM, h1b, h2b);
    k_gemm64<<<dim3((BT / 64) * (3 * DM / 64), 1), 256, 0, stream>>>(
        h1b, wqkvT + (size_t)l * 3 * DM * DM, bqkv + (size_t)l * 3 * DM,
        qkvb, nullptr, BT, 3 * DM, DM, BT / 64, 0);
    k_rope<<<(2 * SEQ * NH * 32) / 256, 256, 0, stream>>>(qkvb, qr, kr);
    k_vtrans<<<dim3(SEQ / 64, 2 * NH), 256, 0, stream>>>(qkvb, vT);
    k_attn<<<dim3(SEQ / 64, 2 * NH), 256, 0, stream>>>(qr, kr, vT, yb);
    k_gemm64<<<dim3((BT / 64) * (DM / 64), 2), 256, 0, stream>>>(
        yb, woT + (size_t)l * DM * DM, bo + (size_t)l * DM,
        nullptr, xf, BT, DM, DM, BT / 64, 2);
    k_gemm64<<<dim3((BT / 64) * (4 * DM / 64), 1), 256, 0, stream>>>(
        h2b, wfcT + (size_t)l * 4 * DM * DM, bfc + (size_t)l * 4 * DM,
        hgel, nullptr, BT, 4 * DM, DM, BT / 64, 1);
    k_gemm64<<<dim3((BT / 64) * (DM / 64), 4), 256, 0, stream>>>(
        hgel, wpT + (size_t)l * 4 * DM * DM, bp + (size_t)l * DM,
        nullptr, xf, BT, DM, 4 * DM, BT / 64, 2);
  }
  k_ln<<<BT, 256, 0, stream>>>(xf, lnfg, lnfb, nullptr, nullptr, xlnf, nullptr);
  if (fast_lm) {
    int nt = (NVOCAB + 127) / 128;
    k_logits<<<(BT / 128) * nt, 256, 0, stream>>>(
        xlnf, wlmT, out, BT, NVOCAB, DM, BT / 128);
  } else {
    k_gemm_f32b<<<dim3(BT / 128, (NVOCAB + 127) / 128), 256, 0, stream>>>(
        xlnf, Wlm, out, BT, NVOCAB, DM);
  }
}